// Round 3
// baseline (1794.418 us; speedup 1.0000x reference)
//
#include <hip/hip_runtime.h>

// ---------------- constants ----------------
#define NTOK 8192
#define NORMC 0.35355339059327373f   // 64^-0.25
#define RATIO 0.0625f                // 256^-0.5
#define KEPS  1e-4f

// ws offsets in 4-byte elements  (total 27987008 ele = 106.8 MB)
#define O_KMAX 0                      // 12 x u32 (encoded max)
#define O_KSUM 64                     // 12*256 f32
#define O_CTX  3136                   // 12*256*64 f32
#define O_ZEND 199744                 // zeroed region end
#define O_COS  199744                 // 8192*32
#define O_SIN  461888                 // 8192*32
#define O_Q    724032                 // 2*8*8192*64
#define O_K    9112640                // K; later reused as attG [16384][384]
#define O_V    17501248
#define O_ATTL 25889856               // 2*2*8192*64 (local heads out)
// end: 27987008

__device__ __forceinline__ unsigned encf(float f) {
    unsigned u = __float_as_uint(f);
    return (u & 0x80000000u) ? ~u : (u | 0x80000000u);
}
__device__ __forceinline__ float decf(unsigned u) {
    return (u & 0x80000000u) ? __uint_as_float(u & 0x7fffffffu) : __uint_as_float(~u);
}

// ---------------- RoPE tables (double precision angles) ----------------
__global__ void k_rope(float* __restrict__ ws) {
    int idx = blockIdx.x * 256 + threadIdx.x;      // 8192*32
    int t = idx >> 5, i = idx & 31;
    double invf = pow(10000.0, -(double)(2 * i) / 64.0);
    double ang = (double)t * invf;
    ws[O_COS + idx] = (float)cos(ang);
    ws[O_SIN + idx] = (float)sin(ang);
}

// ---------------- QKV projection: (16384x512)@(512x512) x3 ----------------
__launch_bounds__(256)
__global__ void k_qkv(const float* __restrict__ x,
                      const float* __restrict__ Wq,
                      const float* __restrict__ Wk,
                      const float* __restrict__ Wv,
                      float* __restrict__ ws) {
    __shared__ float As[16][128];   // [k][m]
    __shared__ float Bs[16][128];   // [k][n]
    const int z = blockIdx.z;
    const float* __restrict__ W = (z == 0) ? Wq : ((z == 1) ? Wk : Wv);
    float* __restrict__ out = ws + ((z == 0) ? O_Q : ((z == 1) ? O_K : O_V));
    const int r0 = blockIdx.x * 128, c0 = blockIdx.y * 128;
    const int tid = threadIdx.x, tx = tid & 15, ty = tid >> 4;
    const int am = tid >> 1, ako = (tid & 1) * 8;
    const int bk = tid >> 4, bjo = (tid & 15) * 8;
    float acc[8][8];
#pragma unroll
    for (int i = 0; i < 8; i++)
#pragma unroll
        for (int j = 0; j < 8; j++) acc[i][j] = 0.f;

    for (int k0 = 0; k0 < 512; k0 += 16) {
        float4 a0 = *(const float4*)(x + (r0 + am) * 512 + k0 + ako);
        float4 a1 = *(const float4*)(x + (r0 + am) * 512 + k0 + ako + 4);
        float4 b0 = *(const float4*)(W + (k0 + bk) * 512 + c0 + bjo);
        float4 b1 = *(const float4*)(W + (k0 + bk) * 512 + c0 + bjo + 4);
        As[ako + 0][am] = a0.x; As[ako + 1][am] = a0.y;
        As[ako + 2][am] = a0.z; As[ako + 3][am] = a0.w;
        As[ako + 4][am] = a1.x; As[ako + 5][am] = a1.y;
        As[ako + 6][am] = a1.z; As[ako + 7][am] = a1.w;
        *(float4*)&Bs[bk][bjo]     = b0;
        *(float4*)&Bs[bk][bjo + 4] = b1;
        __syncthreads();
#pragma unroll
        for (int kk = 0; kk < 16; kk++) {
            float4 a04 = *(float4*)&As[kk][ty * 8];
            float4 a14 = *(float4*)&As[kk][ty * 8 + 4];
            float4 b04 = *(float4*)&Bs[kk][tx * 4];
            float4 b14 = *(float4*)&Bs[kk][64 + tx * 4];
            float a[8] = {a04.x, a04.y, a04.z, a04.w, a14.x, a14.y, a14.z, a14.w};
            float b[8] = {b04.x, b04.y, b04.z, b04.w, b14.x, b14.y, b14.z, b14.w};
#pragma unroll
            for (int i = 0; i < 8; i++)
#pragma unroll
                for (int j = 0; j < 8; j++) acc[i][j] = fmaf(a[i], b[j], acc[i][j]);
        }
        __syncthreads();
    }
    const int bi = r0 >> 13;
#pragma unroll
    for (int i = 0; i < 8; i++) {
        int n = (r0 + ty * 8 + i) & 8191;
        int col0 = c0 + tx * 4;
        int h0 = col0 >> 6, d0 = col0 & 63;
        *(float4*)&out[((bi * 8 + h0) * 8192 + n) * 64 + d0] =
            make_float4(acc[i][0], acc[i][1], acc[i][2], acc[i][3]);
        int col1 = c0 + 64 + tx * 4;
        int h1 = col1 >> 6, d1 = col1 & 63;
        *(float4*)&out[((bi * 8 + h1) * 8192 + n) * 64 + d1] =
            make_float4(acc[i][4], acc[i][5], acc[i][6], acc[i][7]);
    }
}

// ---------------- key-side global max of dd = norm*(K.projT) ----------------
__launch_bounds__(256)
__global__ void k_kmax(const float* __restrict__ proj, float* __restrict__ ws) {
    __shared__ float As[16][64];     // [d][n]
    __shared__ float Bs[16][256];    // [d][j]
    __shared__ unsigned bmax;
    const int bh = blockIdx.x, b = bh / 6, h = bh % 6;
    const float* __restrict__ Kp = ws + O_K + (b * 8 + h) * 8192 * 64;
    const int n0 = blockIdx.y * 64;
    const int tid = threadIdx.x, tx = tid & 15, ty = tid >> 4;
    if (tid == 0) bmax = 0u;
    const int an = tid >> 2, adq = (tid & 3) * 4;
    float acc[4][16];
#pragma unroll
    for (int i = 0; i < 4; i++)
#pragma unroll
        for (int j = 0; j < 16; j++) acc[i][j] = 0.f;

    for (int k0 = 0; k0 < 64; k0 += 16) {
        float4 va = *(const float4*)(Kp + (n0 + an) * 64 + k0 + adq);
        float fp[16];
#pragma unroll
        for (int q = 0; q < 4; q++) {
            float4 p = *(const float4*)(proj + tid * 64 + k0 + q * 4);
            fp[q*4+0] = p.x; fp[q*4+1] = p.y; fp[q*4+2] = p.z; fp[q*4+3] = p.w;
        }
        As[adq + 0][an] = va.x; As[adq + 1][an] = va.y;
        As[adq + 2][an] = va.z; As[adq + 3][an] = va.w;
#pragma unroll
        for (int l = 0; l < 16; l++) Bs[l][tid] = fp[l];
        __syncthreads();
#pragma unroll
        for (int kk = 0; kk < 16; kk++) {
            float4 a4 = *(float4*)&As[kk][ty * 4];
            float a[4] = {a4.x, a4.y, a4.z, a4.w};
#pragma unroll
            for (int g = 0; g < 4; g++) {
                float4 b4 = *(float4*)&Bs[kk][g * 64 + tx * 4];
                float bb[4] = {b4.x, b4.y, b4.z, b4.w};
#pragma unroll
                for (int i = 0; i < 4; i++)
#pragma unroll
                    for (int j = 0; j < 4; j++)
                        acc[i][g * 4 + j] = fmaf(a[i], bb[j], acc[i][g * 4 + j]);
            }
        }
        __syncthreads();
    }
    float m = acc[0][0];
#pragma unroll
    for (int i = 0; i < 4; i++)
#pragma unroll
        for (int j = 0; j < 16; j++) m = fmaxf(m, acc[i][j]);
    atomicMax(&bmax, encf(m * NORMC));
    __syncthreads();
    if (tid == 0) atomicMax((unsigned*)ws + O_KMAX + bh, bmax);
}

// ---------------- key-side: kp, k_sum, ctx = kp^T @ V ----------------
__launch_bounds__(256)
__global__ void k_kctx(const float* __restrict__ proj, float* __restrict__ ws) {
    __shared__ float As1[32][64];        // K rows [d][n]
    __shared__ float BV[4352];           // union: Bs1[32][128] / Vs[64][68]
    __shared__ float kps[64][132];       // kp [n][j] (padded)
    __shared__ float ksum_s[128];
    __shared__ float diag_s[64];
    const int bh = blockIdx.x, b = bh / 6, h = bh % 6;
    const int n0 = blockIdx.y * 256;
    const float* __restrict__ Kp = ws + O_K + (b * 8 + h) * 8192 * 64;
    const float* __restrict__ Vp = ws + O_V + (b * 8 + h) * 8192 * 64;
    const float kmax = decf(((const unsigned*)ws)[O_KMAX + bh]);
    const int tid = threadIdx.x;
    const int tx1 = tid & 15, ty1 = tid >> 4;   // phase1: n rows, j cols
    const int tx2 = tid & 7,  ty2 = tid >> 3;   // phase2: j rows, d cols

    for (int jh = 0; jh < 2; jh++) {
        if (tid < 128) ksum_s[tid] = 0.f;
        float acc2[4][8];
#pragma unroll
        for (int i = 0; i < 4; i++)
#pragma unroll
            for (int j = 0; j < 8; j++) acc2[i][j] = 0.f;

        for (int sub = 0; sub < 4; sub++) {
            const int n0s = n0 + sub * 64;
            if (tid < 64) diag_s[tid] = 0.f;
            float acc1[4][8];
#pragma unroll
            for (int i = 0; i < 4; i++)
#pragma unroll
                for (int j = 0; j < 8; j++) acc1[i][j] = 0.f;
            __syncthreads();

            for (int kt = 0; kt < 2; kt++) {
                const int k0 = kt * 32;
                {   // A: K tile transposed
                    const int sn = tid >> 2, sdq = (tid & 3) * 8;
                    float4 v0 = *(const float4*)(Kp + (n0s + sn) * 64 + k0 + sdq);
                    float4 v1 = *(const float4*)(Kp + (n0s + sn) * 64 + k0 + sdq + 4);
                    As1[sdq + 0][sn] = v0.x; As1[sdq + 1][sn] = v0.y;
                    As1[sdq + 2][sn] = v0.z; As1[sdq + 3][sn] = v0.w;
                    As1[sdq + 4][sn] = v1.x; As1[sdq + 5][sn] = v1.y;
                    As1[sdq + 6][sn] = v1.z; As1[sdq + 7][sn] = v1.w;
                }
                {   // B: proj tile transposed
                    const int sj = tid >> 1, sdo = (tid & 1) * 16;
                    float fp[16];
#pragma unroll
                    for (int q = 0; q < 4; q++) {
                        float4 p = *(const float4*)(proj + (jh * 128 + sj) * 64 + k0 + sdo + q * 4);
                        fp[q*4+0] = p.x; fp[q*4+1] = p.y; fp[q*4+2] = p.z; fp[q*4+3] = p.w;
                    }
#pragma unroll
                    for (int l = 0; l < 16; l++) BV[(sdo + l) * 128 + sj] = fp[l];
                }
                __syncthreads();
                if (tid < 64) {
                    float s = diag_s[tid];
#pragma unroll
                    for (int kk = 0; kk < 32; kk++) { float v = As1[kk][tid]; s = fmaf(v, v, s); }
                    diag_s[tid] = s;
                }
#pragma unroll
                for (int kk = 0; kk < 32; kk++) {
                    float4 a4 = *(float4*)&As1[kk][ty1 * 4];
                    float4 b0 = *(float4*)&BV[kk * 128 + tx1 * 4];
                    float4 b1 = *(float4*)&BV[kk * 128 + 64 + tx1 * 4];
                    float a[4] = {a4.x, a4.y, a4.z, a4.w};
                    float bb[8] = {b0.x, b0.y, b0.z, b0.w, b1.x, b1.y, b1.z, b1.w};
#pragma unroll
                    for (int i = 0; i < 4; i++)
#pragma unroll
                        for (int j = 0; j < 8; j++) acc1[i][j] = fmaf(a[i], bb[j], acc1[i][j]);
                }
                __syncthreads();
            }
            // kp write + ksum
            {
                const int nl = ty1 * 4;
                float colsum[8] = {0.f,0.f,0.f,0.f,0.f,0.f,0.f,0.f};
#pragma unroll
                for (int i = 0; i < 4; i++) {
                    float dg = diag_s[nl + i] * 0.0625f;
                    float kpv[8];
#pragma unroll
                    for (int j = 0; j < 8; j++)
                        kpv[j] = RATIO * (expf(fminf(NORMC * acc1[i][j] - dg - kmax, 0.f)) + KEPS);
                    *(float4*)&kps[nl + i][tx1 * 4]      = make_float4(kpv[0], kpv[1], kpv[2], kpv[3]);
                    *(float4*)&kps[nl + i][64 + tx1 * 4] = make_float4(kpv[4], kpv[5], kpv[6], kpv[7]);
#pragma unroll
                    for (int j = 0; j < 8; j++) colsum[j] += kpv[j];
                }
#pragma unroll
                for (int j = 0; j < 4; j++) {
                    atomicAdd(&ksum_s[tx1 * 4 + j], colsum[j]);
                    atomicAdd(&ksum_s[64 + tx1 * 4 + j], colsum[4 + j]);
                }
            }
            // V staging into BV (stride 68)
            {
                const int vn = tid >> 2, vdq = (tid & 3) * 16;
#pragma unroll
                for (int wv = 0; wv < 4; wv++) {
                    float4 v = *(const float4*)(Vp + (n0s + vn) * 64 + vdq + 4 * wv);
                    *(float4*)&BV[vn * 68 + vdq + 4 * wv] = v;
                }
            }
            __syncthreads();
            // phase2: ctx_partial[j][d] += kp^T @ V
#pragma unroll 8
            for (int kk = 0; kk < 64; kk++) {
                float4 a4 = *(float4*)&kps[kk][ty2 * 4];
                float4 b0 = *(float4*)&BV[kk * 68 + tx2 * 8];
                float4 b1 = *(float4*)&BV[kk * 68 + tx2 * 8 + 4];
                float a[4] = {a4.x, a4.y, a4.z, a4.w};
                float bb[8] = {b0.x, b0.y, b0.z, b0.w, b1.x, b1.y, b1.z, b1.w};
#pragma unroll
                for (int i = 0; i < 4; i++)
#pragma unroll
                    for (int j = 0; j < 8; j++) acc2[i][j] = fmaf(a[i], bb[j], acc2[i][j]);
            }
        }
        __syncthreads();
        // epilogue: global accumulation
        float* __restrict__ ctxp = ws + O_CTX + bh * 16384;
#pragma unroll
        for (int i = 0; i < 4; i++) {
            const int j = jh * 128 + ty2 * 4 + i;
#pragma unroll
            for (int jj = 0; jj < 8; jj++)
                atomicAdd(&ctxp[j * 64 + tx2 * 8 + jj], acc2[i][jj]);
        }
        if (tid < 128) atomicAdd(ws + O_KSUM + bh * 256 + jh * 128 + tid, ksum_s[tid]);
        __syncthreads();
    }
}

// ---------------- query-side: dd, rowmax, qp, attG = qp.ctx / (qp.ksum) ----------------
// writes into the (dead) K region, stride 384
__launch_bounds__(256)
__global__ void k_qout(const float* __restrict__ proj, float* __restrict__ ws) {
    __shared__ float As1[16][64];
    __shared__ float Bs1[16][256];
    __shared__ float qps[64][68];    // qp [n][j-chunk]
    __shared__ float Bs2[64][68];    // ctx chunk [j][d]
    __shared__ float ksum_s[256];
    __shared__ unsigned rmax[64];
    __shared__ float diag_s[64];
    __shared__ float denom_s[64];
    const int bh = blockIdx.x, b = bh / 6, h = bh % 6;
    const int n0 = blockIdx.y * 64;
    const float* __restrict__ Qp = ws + O_Q + (b * 8 + h) * 8192 * 64;
    const float* __restrict__ ctxp = ws + O_CTX + bh * 16384;
    float* __restrict__ attG = ws + O_K;     // [16384][384]
    const int tid = threadIdx.x, tx = tid & 15, ty = tid >> 4;
    if (tid < 64) { rmax[tid] = 0u; diag_s[tid] = 0.f; denom_s[tid] = 0.f; }
    ksum_s[tid] = ws[O_KSUM + bh * 256 + tid];
    float acc1[4][16];
#pragma unroll
    for (int i = 0; i < 4; i++)
#pragma unroll
        for (int j = 0; j < 16; j++) acc1[i][j] = 0.f;
    const int an = tid >> 2, adq = (tid & 3) * 4;

    for (int kt = 0; kt < 4; kt++) {
        const int k0 = kt * 16;
        float4 va = *(const float4*)(Qp + (n0 + an) * 64 + k0 + adq);
        float fp[16];
#pragma unroll
        for (int q = 0; q < 4; q++) {
            float4 p = *(const float4*)(proj + tid * 64 + k0 + q * 4);
            fp[q*4+0] = p.x; fp[q*4+1] = p.y; fp[q*4+2] = p.z; fp[q*4+3] = p.w;
        }
        As1[adq + 0][an] = va.x; As1[adq + 1][an] = va.y;
        As1[adq + 2][an] = va.z; As1[adq + 3][an] = va.w;
#pragma unroll
        for (int l = 0; l < 16; l++) Bs1[l][tid] = fp[l];
        __syncthreads();
        if (tid < 64) {
            float s = diag_s[tid];
#pragma unroll
            for (int kk = 0; kk < 16; kk++) { float v = As1[kk][tid]; s = fmaf(v, v, s); }
            diag_s[tid] = s;
        }
#pragma unroll
        for (int kk = 0; kk < 16; kk++) {
            float4 a4 = *(float4*)&As1[kk][ty * 4];
            float a[4] = {a4.x, a4.y, a4.z, a4.w};
#pragma unroll
            for (int g = 0; g < 4; g++) {
                float4 b4 = *(float4*)&Bs1[kk][g * 64 + tx * 4];
                float bb[4] = {b4.x, b4.y, b4.z, b4.w};
#pragma unroll
                for (int i = 0; i < 4; i++)
#pragma unroll
                    for (int j = 0; j < 4; j++)
                        acc1[i][g * 4 + j] = fmaf(a[i], bb[j], acc1[i][g * 4 + j]);
            }
        }
        __syncthreads();
    }
#pragma unroll
    for (int i = 0; i < 4; i++) {
        float m = acc1[i][0];
#pragma unroll
        for (int c = 1; c < 16; c++) m = fmaxf(m, acc1[i][c]);
        atomicMax(&rmax[ty * 4 + i], encf(m * NORMC));
    }
    __syncthreads();
    float rmx[4], dg[4];
#pragma unroll
    for (int i = 0; i < 4; i++) {
        rmx[i] = decf(rmax[ty * 4 + i]);
        dg[i] = diag_s[ty * 4 + i] * 0.0625f;
    }
    float acc2[4][4];
#pragma unroll
    for (int i = 0; i < 4; i++)
#pragma unroll
        for (int j = 0; j < 4; j++) acc2[i][j] = 0.f;

    for (int jc = 0; jc < 4; jc++) {
#pragma unroll
        for (int i = 0; i < 4; i++) {
            float q0 = RATIO * (expf(fminf(NORMC * acc1[i][jc * 4 + 0] - dg[i] - rmx[i], 0.f)) + KEPS);
            float q1 = RATIO * (expf(fminf(NORMC * acc1[i][jc * 4 + 1] - dg[i] - rmx[i], 0.f)) + KEPS);
            float q2 = RATIO * (expf(fminf(NORMC * acc1[i][jc * 4 + 2] - dg[i] - rmx[i], 0.f)) + KEPS);
            float q3 = RATIO * (expf(fminf(NORMC * acc1[i][jc * 4 + 3] - dg[i] - rmx[i], 0.f)) + KEPS);
            *(float4*)&qps[ty * 4 + i][tx * 4] = make_float4(q0, q1, q2, q3);
            float ds = q0 * ksum_s[jc * 64 + tx * 4 + 0] + q1 * ksum_s[jc * 64 + tx * 4 + 1]
                     + q2 * ksum_s[jc * 64 + tx * 4 + 2] + q3 * ksum_s[jc * 64 + tx * 4 + 3];
            atomicAdd(&denom_s[ty * 4 + i], ds);
        }
        {   // stage ctx chunk
            const int ck = tid >> 2, cdq = (tid & 3) * 16;
#pragma unroll
            for (int wv = 0; wv < 4; wv++) {
                float4 v = *(const float4*)(ctxp + (jc * 64 + ck) * 64 + cdq + 4 * wv);
                *(float4*)&Bs2[ck][cdq + 4 * wv] = v;
            }
        }
        __syncthreads();
#pragma unroll 8
        for (int kk = 0; kk < 64; kk++) {
            float a[4] = {qps[ty * 4 + 0][kk], qps[ty * 4 + 1][kk],
                          qps[ty * 4 + 2][kk], qps[ty * 4 + 3][kk]};
            float4 b4 = *(float4*)&Bs2[kk][tx * 4];
            float bb[4] = {b4.x, b4.y, b4.z, b4.w};
#pragma unroll
            for (int i = 0; i < 4; i++)
#pragma unroll
                for (int j = 0; j < 4; j++) acc2[i][j] = fmaf(a[i], bb[j], acc2[i][j]);
        }
        __syncthreads();
    }
#pragma unroll
    for (int i = 0; i < 4; i++) {
        int n = n0 + ty * 4 + i;
        float inv = 1.0f / fmaxf(denom_s[ty * 4 + i], 1e-30f);
        *(float4*)&attG[(b * 8192 + n) * 384 + h * 64 + tx * 4] =
            make_float4(acc2[i][0] * inv, acc2[i][1] * inv, acc2[i][2] * inv, acc2[i][3] * inv);
    }
}

// ---------------- local windowed attention w/ RoPE, heads 6..7 ----------------
// 1 query/thread, 128 threads; runs BEFORE k_qout (which overwrites K region)
__launch_bounds__(128)
__global__ void k_local(float* __restrict__ ws) {
    __shared__ float ks[64][68];
    __shared__ float vs[64][68];
    const int bhp = blockIdx.x, b = bhp >> 1, lh = bhp & 1, h = 6 + lh;
    const int w = blockIdx.y, half = blockIdx.z;
    const float* __restrict__ Qb = ws + O_Q + (b * 8 + h) * 8192 * 64;
    const float* __restrict__ Kb = ws + O_K + (b * 8 + h) * 8192 * 64;
    const float* __restrict__ Vb = ws + O_V + (b * 8 + h) * 8192 * 64;
    const float* __restrict__ cosT = ws + O_COS;
    const float* __restrict__ sinT = ws + O_SIN;
    const int t = threadIdx.x;
    const int qi = w * 256 + half * 128 + t;
    float qa[64], oa[64];
#pragma unroll
    for (int d = 0; d < 64; d++) oa[d] = 0.f;
#pragma unroll
    for (int dq = 0; dq < 32; dq += 4) {
        float4 c4 = *(const float4*)(cosT + qi * 32 + dq);
        float4 s4 = *(const float4*)(sinT + qi * 32 + dq);
        float4 x0 = *(const float4*)(Qb + qi * 64 + dq);
        float4 x1 = *(const float4*)(Qb + qi * 64 + 32 + dq);
        qa[dq + 0] = x0.x * c4.x - x1.x * s4.x; qa[32 + dq + 0] = x1.x * c4.x + x0.x * s4.x;
        qa[dq + 1] = x0.y * c4.y - x1.y * s4.y; qa[32 + dq + 1] = x1.y * c4.y + x0.y * s4.y;
        qa[dq + 2] = x0.z * c4.z - x1.z * s4.z; qa[32 + dq + 2] = x1.z * c4.z + x0.z * s4.z;
        qa[dq + 3] = x0.w * c4.w - x1.w * s4.w; qa[32 + dq + 3] = x1.w * c4.w + x0.w * s4.w;
    }
    float ma = -1e30f, la = 0.f;

    for (int c = 0; c < 12; c++) {
        int kp0 = (w - 1) * 256 + c * 64;
        if (kp0 < 0 || kp0 >= 8192) continue;   // masked/padded windows (block-uniform)
        if (t < 64) {
            int kpos = kp0 + t;
#pragma unroll
            for (int dq = 0; dq < 32; dq += 4) {
                float4 c4 = *(const float4*)(cosT + kpos * 32 + dq);
                float4 s4 = *(const float4*)(sinT + kpos * 32 + dq);
                float4 x0 = *(const float4*)(Kb + kpos * 64 + dq);
                float4 x1 = *(const float4*)(Kb + kpos * 64 + 32 + dq);
                *(float4*)&ks[t][dq] = make_float4(x0.x * c4.x - x1.x * s4.x,
                                                   x0.y * c4.y - x1.y * s4.y,
                                                   x0.z * c4.z - x1.z * s4.z,
                                                   x0.w * c4.w - x1.w * s4.w);
                *(float4*)&ks[t][32 + dq] = make_float4(x1.x * c4.x + x0.x * s4.x,
                                                        x1.y * c4.y + x0.y * s4.y,
                                                        x1.z * c4.z + x0.z * s4.z,
                                                        x1.w * c4.w + x0.w * s4.w);
            }
        } else {
            int vn = t - 64, kpos = kp0 + vn;
#pragma unroll
            for (int dq = 0; dq < 64; dq += 4)
                *(float4*)&vs[vn][dq] = *(const float4*)(Vb + kpos * 64 + dq);
        }
        __syncthreads();
        for (int jj = 0; jj < 64; jj++) {
            float da = 0.f;
#pragma unroll
            for (int dq = 0; dq < 64; dq += 4) {
                float4 kv = *(float4*)&ks[jj][dq];
                da = fmaf(qa[dq+0], kv.x, fmaf(qa[dq+1], kv.y, fmaf(qa[dq+2], kv.z, fmaf(qa[dq+3], kv.w, da))));
            }
            float sa = da * 0.125f;
            float mna = fmaxf(ma, sa);
            float ala = expf(ma - mna), pa = expf(sa - mna);
            la = la * ala + pa; ma = mna;
#pragma unroll
            for (int dq = 0; dq < 64; dq += 4) {
                float4 vv = *(float4*)&vs[jj][dq];
                oa[dq+0] = fmaf(oa[dq+0], ala, pa * vv.x);
                oa[dq+1] = fmaf(oa[dq+1], ala, pa * vv.y);
                oa[dq+2] = fmaf(oa[dq+2], ala, pa * vv.z);
                oa[dq+3] = fmaf(oa[dq+3], ala, pa * vv.w);
            }
        }
        __syncthreads();
    }
    float ira = 1.f / fmaxf(la, 1e-30f);
    float* __restrict__ attL = ws + O_ATTL;   // [2][2][8192][64]
#pragma unroll
    for (int dq = 0; dq < 64; dq += 4) {
        *(float4*)&attL[((b * 2 + lh) * 8192 + qi) * 64 + dq] =
            make_float4(oa[dq] * ira, oa[dq+1] * ira, oa[dq+2] * ira, oa[dq+3] * ira);
    }
}

// ---------------- output projection + bias ----------------
__launch_bounds__(256)
__global__ void k_out(const float* __restrict__ Wo,
                      const float* __restrict__ bo,
                      const float* __restrict__ ws,
                      float* __restrict__ out) {
    __shared__ float As[16][128];
    __shared__ float Bs[16][128];
    const float* __restrict__ attG = ws + O_K;      // [16384][384]
    const float* __restrict__ attL = ws + O_ATTL;   // [4][8192][64]
    const int r0 = blockIdx.x * 128, c0 = blockIdx.y * 128;
    const int tid = threadIdx.x, tx = tid & 15, ty = tid >> 4;
    const int am = tid >> 1, ako = (tid & 1) * 8;
    const int bk = tid >> 4, bjo = (tid & 15) * 8;
    float acc[8][8];
#pragma unroll
    for (int i = 0; i < 8; i++)
#pragma unroll
        for (int j = 0; j < 8; j++) acc[i][j] = 0.f;

    for (int k0 = 0; k0 < 512; k0 += 16) {
        const int row = r0 + am;
        float4 a0, a1;
        if (k0 < 384) {
            a0 = *(const float4*)(attG + row * 384 + k0 + ako);
            a1 = *(const float4*)(attG + row * 384 + k0 + ako + 4);
        } else {
            const int bb = row >> 13, nn = row & 8191;
            const int kk0 = k0 + ako - 384;
            const int lhh = kk0 >> 6, dd = kk0 & 63;
            const float* src = attL + ((bb * 2 + lhh) * 8192 + nn) * 64 + dd;
            a0 = *(const float4*)(src);
            a1 = *(const float4*)(src + 4);
        }
        float4 b0 = *(const float4*)(Wo + (k0 + bk) * 512 + c0 + bjo);
        float4 b1 = *(const float4*)(Wo + (k0 + bk) * 512 + c0 + bjo + 4);
        As[ako + 0][am] = a0.x; As[ako + 1][am] = a0.y;
        As[ako + 2][am] = a0.z; As[ako + 3][am] = a0.w;
        As[ako + 4][am] = a1.x; As[ako + 5][am] = a1.y;
        As[ako + 6][am] = a1.z; As[ako + 7][am] = a1.w;
        *(float4*)&Bs[bk][bjo]     = b0;
        *(float4*)&Bs[bk][bjo + 4] = b1;
        __syncthreads();
#pragma unroll
        for (int kk = 0; kk < 16; kk++) {
            float4 a04 = *(float4*)&As[kk][ty * 8];
            float4 a14 = *(float4*)&As[kk][ty * 8 + 4];
            float4 b04 = *(float4*)&Bs[kk][tx * 4];
            float4 b14 = *(float4*)&Bs[kk][64 + tx * 4];
            float a[8] = {a04.x, a04.y, a04.z, a04.w, a14.x, a14.y, a14.z, a14.w};
            float b[8] = {b04.x, b04.y, b04.z, b04.w, b14.x, b14.y, b14.z, b14.w};
#pragma unroll
            for (int i = 0; i < 8; i++)
#pragma unroll
                for (int j = 0; j < 8; j++) acc[i][j] = fmaf(a[i], b[j], acc[i][j]);
        }
        __syncthreads();
    }
    const int col0 = c0 + tx * 4, col1 = c0 + 64 + tx * 4;
    float4 bo0 = *(const float4*)(bo + col0);
    float4 bo1 = *(const float4*)(bo + col1);
#pragma unroll
    for (int i = 0; i < 8; i++) {
        int r = r0 + ty * 8 + i;
        *(float4*)&out[r * 512 + col0] =
            make_float4(acc[i][0] + bo0.x, acc[i][1] + bo0.y, acc[i][2] + bo0.z, acc[i][3] + bo0.w);
        *(float4*)&out[r * 512 + col1] =
            make_float4(acc[i][4] + bo1.x, acc[i][5] + bo1.y, acc[i][6] + bo1.z, acc[i][7] + bo1.w);
    }
}

extern "C" void kernel_launch(void* const* d_in, const int* in_sizes, int n_in,
                              void* d_out, int out_size, void* d_ws, size_t ws_size,
                              hipStream_t stream) {
    const float* x    = (const float*)d_in[0];
    const float* Wq   = (const float*)d_in[1];
    const float* Wk   = (const float*)d_in[2];
    const float* Wv   = (const float*)d_in[3];
    const float* Wo   = (const float*)d_in[4];
    const float* bo   = (const float*)d_in[5];
    const float* proj = (const float*)d_in[6];
    float* ws = (float*)d_ws;
    float* out = (float*)d_out;

    hipMemsetAsync(d_ws, 0, (size_t)O_ZEND * 4, stream);                 // kmax/ksum/ctx
    hipLaunchKernelGGL(k_rope, dim3(1024), dim3(256), 0, stream, ws);
    hipLaunchKernelGGL(k_qkv,  dim3(128, 4, 3), dim3(256), 0, stream, x, Wq, Wk, Wv, ws);
    hipLaunchKernelGGL(k_kmax, dim3(12, 128), dim3(256), 0, stream, proj, ws);
    hipLaunchKernelGGL(k_kctx, dim3(12, 32), dim3(256), 0, stream, proj, ws);
    hipLaunchKernelGGL(k_local, dim3(4, 32, 2), dim3(128), 0, stream, ws);   // before k_qout!
    hipLaunchKernelGGL(k_qout, dim3(12, 128), dim3(256), 0, stream, proj, ws);
    hipLaunchKernelGGL(k_out,  dim3(128, 4), dim3(256), 0, stream, Wo, bo, ws, out);
}

// Round 4
// 1071.933 us; speedup vs baseline: 1.6740x; 1.6740x over previous
//
#include <hip/hip_runtime.h>

// ---------------- constants ----------------
#define NTOK 8192
#define NORMC 0.35355339059327373f   // 64^-0.25
#define RATIO 0.0625f                // 256^-0.5
#define KEPS  1e-4f

// ws offsets in 4-byte elements  (total 27987008 ele = 106.8 MB)
#define O_KMAX 0                      // 12 x u32 (encoded max)
#define O_KSUM 64                     // 12*256 f32
#define O_CTX  3136                   // 12*256*64 f32
#define O_ZEND 199744                 // zeroed region end
#define O_COS  199744                 // 8192*32
#define O_SIN  461888                 // 8192*32
#define O_Q    724032                 // 2*8*8192*64
#define O_K    9112640                // K; later reused as attG [16384][384]
#define O_V    17501248
#define O_ATTL 25889856               // 2*2*8192*64 (local heads out)
// end: 27987008

__device__ __forceinline__ unsigned encf(float f) {
    unsigned u = __float_as_uint(f);
    return (u & 0x80000000u) ? ~u : (u | 0x80000000u);
}
__device__ __forceinline__ float decf(unsigned u) {
    return (u & 0x80000000u) ? __uint_as_float(u & 0x7fffffffu) : __uint_as_float(~u);
}

// ---------------- RoPE tables (double precision angles) ----------------
__global__ void k_rope(float* __restrict__ ws) {
    int idx = blockIdx.x * 256 + threadIdx.x;      // 8192*32
    int t = idx >> 5, i = idx & 31;
    double invf = pow(10000.0, -(double)(2 * i) / 64.0);
    double ang = (double)t * invf;
    ws[O_COS + idx] = (float)cos(ang);
    ws[O_SIN + idx] = (float)sin(ang);
}

// ---------------- QKV projection: (16384x512)@(512x512) x3 ----------------
__launch_bounds__(256)
__global__ void k_qkv(const float* __restrict__ x,
                      const float* __restrict__ Wq,
                      const float* __restrict__ Wk,
                      const float* __restrict__ Wv,
                      float* __restrict__ ws) {
    __shared__ float As[16][128];   // [k][m]
    __shared__ float Bs[16][128];   // [k][n]
    const int z = blockIdx.z;
    const float* __restrict__ W = (z == 0) ? Wq : ((z == 1) ? Wk : Wv);
    float* __restrict__ out = ws + ((z == 0) ? O_Q : ((z == 1) ? O_K : O_V));
    const int r0 = blockIdx.x * 128, c0 = blockIdx.y * 128;
    const int tid = threadIdx.x, tx = tid & 15, ty = tid >> 4;
    const int am = tid >> 1, ako = (tid & 1) * 8;
    const int bk = tid >> 4, bjo = (tid & 15) * 8;
    float acc[8][8];
#pragma unroll
    for (int i = 0; i < 8; i++)
#pragma unroll
        for (int j = 0; j < 8; j++) acc[i][j] = 0.f;

    for (int k0 = 0; k0 < 512; k0 += 16) {
        float4 a0 = *(const float4*)(x + (r0 + am) * 512 + k0 + ako);
        float4 a1 = *(const float4*)(x + (r0 + am) * 512 + k0 + ako + 4);
        float4 b0 = *(const float4*)(W + (k0 + bk) * 512 + c0 + bjo);
        float4 b1 = *(const float4*)(W + (k0 + bk) * 512 + c0 + bjo + 4);
        As[ako + 0][am] = a0.x; As[ako + 1][am] = a0.y;
        As[ako + 2][am] = a0.z; As[ako + 3][am] = a0.w;
        As[ako + 4][am] = a1.x; As[ako + 5][am] = a1.y;
        As[ako + 6][am] = a1.z; As[ako + 7][am] = a1.w;
        *(float4*)&Bs[bk][bjo]     = b0;
        *(float4*)&Bs[bk][bjo + 4] = b1;
        __syncthreads();
#pragma unroll
        for (int kk = 0; kk < 16; kk++) {
            float4 a04 = *(float4*)&As[kk][ty * 8];
            float4 a14 = *(float4*)&As[kk][ty * 8 + 4];
            float4 b04 = *(float4*)&Bs[kk][tx * 4];
            float4 b14 = *(float4*)&Bs[kk][64 + tx * 4];
            float a[8] = {a04.x, a04.y, a04.z, a04.w, a14.x, a14.y, a14.z, a14.w};
            float b[8] = {b04.x, b04.y, b04.z, b04.w, b14.x, b14.y, b14.z, b14.w};
#pragma unroll
            for (int i = 0; i < 8; i++)
#pragma unroll
                for (int j = 0; j < 8; j++) acc[i][j] = fmaf(a[i], b[j], acc[i][j]);
        }
        __syncthreads();
    }
    const int bi = r0 >> 13;
#pragma unroll
    for (int i = 0; i < 8; i++) {
        int n = (r0 + ty * 8 + i) & 8191;
        int col0 = c0 + tx * 4;
        int h0 = col0 >> 6, d0 = col0 & 63;
        *(float4*)&out[((bi * 8 + h0) * 8192 + n) * 64 + d0] =
            make_float4(acc[i][0], acc[i][1], acc[i][2], acc[i][3]);
        int col1 = c0 + 64 + tx * 4;
        int h1 = col1 >> 6, d1 = col1 & 63;
        *(float4*)&out[((bi * 8 + h1) * 8192 + n) * 64 + d1] =
            make_float4(acc[i][4], acc[i][5], acc[i][6], acc[i][7]);
    }
}

// ---------------- key-side global max of dd = norm*(K.projT) ----------------
__launch_bounds__(256)
__global__ void k_kmax(const float* __restrict__ proj, float* __restrict__ ws) {
    __shared__ float As[16][64];     // [d][n]
    __shared__ float Bs[16][256];    // [d][j]
    __shared__ unsigned bmax;
    const int bh = blockIdx.x, b = bh / 6, h = bh % 6;
    const float* __restrict__ Kp = ws + O_K + (b * 8 + h) * 8192 * 64;
    const int n0 = blockIdx.y * 64;
    const int tid = threadIdx.x, tx = tid & 15, ty = tid >> 4;
    if (tid == 0) bmax = 0u;
    const int an = tid >> 2, adq = (tid & 3) * 4;
    float acc[4][16];
#pragma unroll
    for (int i = 0; i < 4; i++)
#pragma unroll
        for (int j = 0; j < 16; j++) acc[i][j] = 0.f;

    for (int k0 = 0; k0 < 64; k0 += 16) {
        float4 va = *(const float4*)(Kp + (n0 + an) * 64 + k0 + adq);
        float fp[16];
#pragma unroll
        for (int q = 0; q < 4; q++) {
            float4 p = *(const float4*)(proj + tid * 64 + k0 + q * 4);
            fp[q*4+0] = p.x; fp[q*4+1] = p.y; fp[q*4+2] = p.z; fp[q*4+3] = p.w;
        }
        As[adq + 0][an] = va.x; As[adq + 1][an] = va.y;
        As[adq + 2][an] = va.z; As[adq + 3][an] = va.w;
#pragma unroll
        for (int l = 0; l < 16; l++) Bs[l][tid] = fp[l];
        __syncthreads();
#pragma unroll
        for (int kk = 0; kk < 16; kk++) {
            float4 a4 = *(float4*)&As[kk][ty * 4];
            float a[4] = {a4.x, a4.y, a4.z, a4.w};
#pragma unroll
            for (int g = 0; g < 4; g++) {
                float4 b4 = *(float4*)&Bs[kk][g * 64 + tx * 4];
                float bb[4] = {b4.x, b4.y, b4.z, b4.w};
#pragma unroll
                for (int i = 0; i < 4; i++)
#pragma unroll
                    for (int j = 0; j < 4; j++)
                        acc[i][g * 4 + j] = fmaf(a[i], bb[j], acc[i][g * 4 + j]);
            }
        }
        __syncthreads();
    }
    float m = acc[0][0];
#pragma unroll
    for (int i = 0; i < 4; i++)
#pragma unroll
        for (int j = 0; j < 16; j++) m = fmaxf(m, acc[i][j]);
    atomicMax(&bmax, encf(m * NORMC));
    __syncthreads();
    if (tid == 0) atomicMax((unsigned*)ws + O_KMAX + bh, bmax);
}

// ---------------- key-side: kp, k_sum, ctx = kp^T @ V ----------------
__launch_bounds__(256)
__global__ void k_kctx(const float* __restrict__ proj, float* __restrict__ ws) {
    __shared__ float As1[32][64];        // K rows [d][n]
    __shared__ float BV[4352];           // union: Bs1[32][128] / Vs[64][68]
    __shared__ float kps[64][132];       // kp [n][j] (padded)
    __shared__ float ksum_s[128];
    __shared__ float diag_s[64];
    const int bh = blockIdx.x, b = bh / 6, h = bh % 6;
    const int n0 = blockIdx.y * 256;
    const float* __restrict__ Kp = ws + O_K + (b * 8 + h) * 8192 * 64;
    const float* __restrict__ Vp = ws + O_V + (b * 8 + h) * 8192 * 64;
    const float kmax = decf(((const unsigned*)ws)[O_KMAX + bh]);
    const int tid = threadIdx.x;
    const int tx1 = tid & 15, ty1 = tid >> 4;   // phase1: n rows, j cols
    const int tx2 = tid & 7,  ty2 = tid >> 3;   // phase2: j rows, d cols

    for (int jh = 0; jh < 2; jh++) {
        if (tid < 128) ksum_s[tid] = 0.f;
        float acc2[4][8];
#pragma unroll
        for (int i = 0; i < 4; i++)
#pragma unroll
            for (int j = 0; j < 8; j++) acc2[i][j] = 0.f;

        for (int sub = 0; sub < 4; sub++) {
            const int n0s = n0 + sub * 64;
            if (tid < 64) diag_s[tid] = 0.f;
            float acc1[4][8];
#pragma unroll
            for (int i = 0; i < 4; i++)
#pragma unroll
                for (int j = 0; j < 8; j++) acc1[i][j] = 0.f;
            __syncthreads();

            for (int kt = 0; kt < 2; kt++) {
                const int k0 = kt * 32;
                {   // A: K tile transposed
                    const int sn = tid >> 2, sdq = (tid & 3) * 8;
                    float4 v0 = *(const float4*)(Kp + (n0s + sn) * 64 + k0 + sdq);
                    float4 v1 = *(const float4*)(Kp + (n0s + sn) * 64 + k0 + sdq + 4);
                    As1[sdq + 0][sn] = v0.x; As1[sdq + 1][sn] = v0.y;
                    As1[sdq + 2][sn] = v0.z; As1[sdq + 3][sn] = v0.w;
                    As1[sdq + 4][sn] = v1.x; As1[sdq + 5][sn] = v1.y;
                    As1[sdq + 6][sn] = v1.z; As1[sdq + 7][sn] = v1.w;
                }
                {   // B: proj tile transposed
                    const int sj = tid >> 1, sdo = (tid & 1) * 16;
                    float fp[16];
#pragma unroll
                    for (int q = 0; q < 4; q++) {
                        float4 p = *(const float4*)(proj + (jh * 128 + sj) * 64 + k0 + sdo + q * 4);
                        fp[q*4+0] = p.x; fp[q*4+1] = p.y; fp[q*4+2] = p.z; fp[q*4+3] = p.w;
                    }
#pragma unroll
                    for (int l = 0; l < 16; l++) BV[(sdo + l) * 128 + sj] = fp[l];
                }
                __syncthreads();
                if (tid < 64) {
                    float s = diag_s[tid];
#pragma unroll
                    for (int kk = 0; kk < 32; kk++) { float v = As1[kk][tid]; s = fmaf(v, v, s); }
                    diag_s[tid] = s;
                }
#pragma unroll
                for (int kk = 0; kk < 32; kk++) {
                    float4 a4 = *(float4*)&As1[kk][ty1 * 4];
                    float4 b0 = *(float4*)&BV[kk * 128 + tx1 * 4];
                    float4 b1 = *(float4*)&BV[kk * 128 + 64 + tx1 * 4];
                    float a[4] = {a4.x, a4.y, a4.z, a4.w};
                    float bb[8] = {b0.x, b0.y, b0.z, b0.w, b1.x, b1.y, b1.z, b1.w};
#pragma unroll
                    for (int i = 0; i < 4; i++)
#pragma unroll
                        for (int j = 0; j < 8; j++) acc1[i][j] = fmaf(a[i], bb[j], acc1[i][j]);
                }
                __syncthreads();
            }
            // kp write + ksum
            {
                const int nl = ty1 * 4;
                float colsum[8] = {0.f,0.f,0.f,0.f,0.f,0.f,0.f,0.f};
#pragma unroll
                for (int i = 0; i < 4; i++) {
                    float dg = diag_s[nl + i] * 0.0625f;
                    float kpv[8];
#pragma unroll
                    for (int j = 0; j < 8; j++)
                        kpv[j] = RATIO * (expf(fminf(NORMC * acc1[i][j] - dg - kmax, 0.f)) + KEPS);
                    *(float4*)&kps[nl + i][tx1 * 4]      = make_float4(kpv[0], kpv[1], kpv[2], kpv[3]);
                    *(float4*)&kps[nl + i][64 + tx1 * 4] = make_float4(kpv[4], kpv[5], kpv[6], kpv[7]);
#pragma unroll
                    for (int j = 0; j < 8; j++) colsum[j] += kpv[j];
                }
#pragma unroll
                for (int j = 0; j < 4; j++) {
                    atomicAdd(&ksum_s[tx1 * 4 + j], colsum[j]);
                    atomicAdd(&ksum_s[64 + tx1 * 4 + j], colsum[4 + j]);
                }
            }
            // V staging into BV (stride 68)
            {
                const int vn = tid >> 2, vdq = (tid & 3) * 16;
#pragma unroll
                for (int wv = 0; wv < 4; wv++) {
                    float4 v = *(const float4*)(Vp + (n0s + vn) * 64 + vdq + 4 * wv);
                    *(float4*)&BV[vn * 68 + vdq + 4 * wv] = v;
                }
            }
            __syncthreads();
            // phase2: ctx_partial[j][d] += kp^T @ V
#pragma unroll 8
            for (int kk = 0; kk < 64; kk++) {
                float4 a4 = *(float4*)&kps[kk][ty2 * 4];
                float4 b0 = *(float4*)&BV[kk * 68 + tx2 * 8];
                float4 b1 = *(float4*)&BV[kk * 68 + tx2 * 8 + 4];
                float a[4] = {a4.x, a4.y, a4.z, a4.w};
                float bb[8] = {b0.x, b0.y, b0.z, b0.w, b1.x, b1.y, b1.z, b1.w};
#pragma unroll
                for (int i = 0; i < 4; i++)
#pragma unroll
                    for (int j = 0; j < 8; j++) acc2[i][j] = fmaf(a[i], bb[j], acc2[i][j]);
            }
        }
        __syncthreads();
        // epilogue: global accumulation
        float* __restrict__ ctxp = ws + O_CTX + bh * 16384;
#pragma unroll
        for (int i = 0; i < 4; i++) {
            const int j = jh * 128 + ty2 * 4 + i;
#pragma unroll
            for (int jj = 0; jj < 8; jj++)
                atomicAdd(&ctxp[j * 64 + tx2 * 8 + jj], acc2[i][jj]);
        }
        if (tid < 128) atomicAdd(ws + O_KSUM + bh * 256 + jh * 128 + tid, ksum_s[tid]);
        __syncthreads();
    }
}

// ---------------- query-side: dd, rowmax, qp, attG = qp.ctx / (qp.ksum) ----------------
// writes into the (dead) K region, stride 384
__launch_bounds__(256)
__global__ void k_qout(const float* __restrict__ proj, float* __restrict__ ws) {
    __shared__ float As1[16][64];
    __shared__ float Bs1[16][256];
    __shared__ float qps[64][68];    // qp [n][j-chunk]
    __shared__ float Bs2[64][68];    // ctx chunk [j][d]
    __shared__ float ksum_s[256];
    __shared__ unsigned rmax[64];
    __shared__ float diag_s[64];
    __shared__ float denom_s[64];
    const int bh = blockIdx.x, b = bh / 6, h = bh % 6;
    const int n0 = blockIdx.y * 64;
    const float* __restrict__ Qp = ws + O_Q + (b * 8 + h) * 8192 * 64;
    const float* __restrict__ ctxp = ws + O_CTX + bh * 16384;
    float* __restrict__ attG = ws + O_K;     // [16384][384]
    const int tid = threadIdx.x, tx = tid & 15, ty = tid >> 4;
    if (tid < 64) { rmax[tid] = 0u; diag_s[tid] = 0.f; denom_s[tid] = 0.f; }
    ksum_s[tid] = ws[O_KSUM + bh * 256 + tid];
    float acc1[4][16];
#pragma unroll
    for (int i = 0; i < 4; i++)
#pragma unroll
        for (int j = 0; j < 16; j++) acc1[i][j] = 0.f;
    const int an = tid >> 2, adq = (tid & 3) * 4;

    for (int kt = 0; kt < 4; kt++) {
        const int k0 = kt * 16;
        float4 va = *(const float4*)(Qp + (n0 + an) * 64 + k0 + adq);
        float fp[16];
#pragma unroll
        for (int q = 0; q < 4; q++) {
            float4 p = *(const float4*)(proj + tid * 64 + k0 + q * 4);
            fp[q*4+0] = p.x; fp[q*4+1] = p.y; fp[q*4+2] = p.z; fp[q*4+3] = p.w;
        }
        As1[adq + 0][an] = va.x; As1[adq + 1][an] = va.y;
        As1[adq + 2][an] = va.z; As1[adq + 3][an] = va.w;
#pragma unroll
        for (int l = 0; l < 16; l++) Bs1[l][tid] = fp[l];
        __syncthreads();
        if (tid < 64) {
            float s = diag_s[tid];
#pragma unroll
            for (int kk = 0; kk < 16; kk++) { float v = As1[kk][tid]; s = fmaf(v, v, s); }
            diag_s[tid] = s;
        }
#pragma unroll
        for (int kk = 0; kk < 16; kk++) {
            float4 a4 = *(float4*)&As1[kk][ty * 4];
            float a[4] = {a4.x, a4.y, a4.z, a4.w};
#pragma unroll
            for (int g = 0; g < 4; g++) {
                float4 b4 = *(float4*)&Bs1[kk][g * 64 + tx * 4];
                float bb[4] = {b4.x, b4.y, b4.z, b4.w};
#pragma unroll
                for (int i = 0; i < 4; i++)
#pragma unroll
                    for (int j = 0; j < 4; j++)
                        acc1[i][g * 4 + j] = fmaf(a[i], bb[j], acc1[i][g * 4 + j]);
            }
        }
        __syncthreads();
    }
#pragma unroll
    for (int i = 0; i < 4; i++) {
        float m = acc1[i][0];
#pragma unroll
        for (int c = 1; c < 16; c++) m = fmaxf(m, acc1[i][c]);
        atomicMax(&rmax[ty * 4 + i], encf(m * NORMC));
    }
    __syncthreads();
    float rmx[4], dg[4];
#pragma unroll
    for (int i = 0; i < 4; i++) {
        rmx[i] = decf(rmax[ty * 4 + i]);
        dg[i] = diag_s[ty * 4 + i] * 0.0625f;
    }
    float acc2[4][4];
#pragma unroll
    for (int i = 0; i < 4; i++)
#pragma unroll
        for (int j = 0; j < 4; j++) acc2[i][j] = 0.f;

    for (int jc = 0; jc < 4; jc++) {
#pragma unroll
        for (int i = 0; i < 4; i++) {
            float q0 = RATIO * (expf(fminf(NORMC * acc1[i][jc * 4 + 0] - dg[i] - rmx[i], 0.f)) + KEPS);
            float q1 = RATIO * (expf(fminf(NORMC * acc1[i][jc * 4 + 1] - dg[i] - rmx[i], 0.f)) + KEPS);
            float q2 = RATIO * (expf(fminf(NORMC * acc1[i][jc * 4 + 2] - dg[i] - rmx[i], 0.f)) + KEPS);
            float q3 = RATIO * (expf(fminf(NORMC * acc1[i][jc * 4 + 3] - dg[i] - rmx[i], 0.f)) + KEPS);
            *(float4*)&qps[ty * 4 + i][tx * 4] = make_float4(q0, q1, q2, q3);
            float ds = q0 * ksum_s[jc * 64 + tx * 4 + 0] + q1 * ksum_s[jc * 64 + tx * 4 + 1]
                     + q2 * ksum_s[jc * 64 + tx * 4 + 2] + q3 * ksum_s[jc * 64 + tx * 4 + 3];
            atomicAdd(&denom_s[ty * 4 + i], ds);
        }
        {   // stage ctx chunk
            const int ck = tid >> 2, cdq = (tid & 3) * 16;
#pragma unroll
            for (int wv = 0; wv < 4; wv++) {
                float4 v = *(const float4*)(ctxp + (jc * 64 + ck) * 64 + cdq + 4 * wv);
                *(float4*)&Bs2[ck][cdq + 4 * wv] = v;
            }
        }
        __syncthreads();
#pragma unroll 8
        for (int kk = 0; kk < 64; kk++) {
            float a[4] = {qps[ty * 4 + 0][kk], qps[ty * 4 + 1][kk],
                          qps[ty * 4 + 2][kk], qps[ty * 4 + 3][kk]};
            float4 b4 = *(float4*)&Bs2[kk][tx * 4];
            float bb[4] = {b4.x, b4.y, b4.z, b4.w};
#pragma unroll
            for (int i = 0; i < 4; i++)
#pragma unroll
                for (int j = 0; j < 4; j++) acc2[i][j] = fmaf(a[i], bb[j], acc2[i][j]);
        }
        __syncthreads();
    }
#pragma unroll
    for (int i = 0; i < 4; i++) {
        int n = n0 + ty * 4 + i;
        float inv = 1.0f / fmaxf(denom_s[ty * 4 + i], 1e-30f);
        *(float4*)&attG[(b * 8192 + n) * 384 + h * 64 + tx * 4] =
            make_float4(acc2[i][0] * inv, acc2[i][1] * inv, acc2[i][2] * inv, acc2[i][3] * inv);
    }
}

// ---------------- local windowed attention w/ RoPE, heads 6..7 ----------------
// Flash-tile rewrite: block = 64 queries x 256 threads, 4x4 register GEMMs.
// Grid 4 x 128 = 512 blocks, ~52.5 KB LDS -> 3 blocks/CU.
// Runs BEFORE k_qout (which overwrites the K region).
__launch_bounds__(256)
__global__ void k_local(float* __restrict__ ws) {
    __shared__ float Qt[64][64];     // RoPE'd Q, [d][q]
    __shared__ float KtP[64][68];    // RoPE'd K [d][k]; after rowmax barrier reused as pT [k][q]
    __shared__ float Vs[64][68];     // V chunk [k][d]
    __shared__ unsigned rmax_s[64];
    __shared__ float m_s[64], l_s[64], lsum_s[64];
    const int bhp = blockIdx.x, b = bhp >> 1, lh = bhp & 1, h = 6 + lh;
    const int tile = blockIdx.y;                 // 0..127 (64-query tiles)
    const int w = tile >> 2;                     // window index
    const int q0 = tile * 64;
    const float* __restrict__ Qb = ws + O_Q + (b * 8 + h) * 8192 * 64;
    const float* __restrict__ Kb = ws + O_K + (b * 8 + h) * 8192 * 64;
    const float* __restrict__ Vb = ws + O_V + (b * 8 + h) * 8192 * 64;
    const float* __restrict__ cosT = ws + O_COS;
    const float* __restrict__ sinT = ws + O_SIN;
    const int tid = threadIdx.x, tx = tid & 15, ty = tid >> 4;
    const int row = tid >> 2, dq = (tid & 3) * 16;   // staging: 4 threads x 16 dims per row
    const int e = dq & 31;
    const int comp = (dq < 32) ? dq + 32 : dq - 32;
    const float sgn = (dq < 32) ? -1.f : 1.f;

    {   // stage Q tile with RoPE, transposed [d][q]
        const int qpos = q0 + row;
        const float* bp = Qb + qpos * 64;
        const float* cp = cosT + qpos * 32 + e;
        const float* sp = sinT + qpos * 32 + e;
#pragma unroll
        for (int w4 = 0; w4 < 4; w4++) {
            float4 c4 = *(const float4*)(cp + 4 * w4);
            float4 s4 = *(const float4*)(sp + 4 * w4);
            float4 xa = *(const float4*)(bp + dq + 4 * w4);
            float4 xb = *(const float4*)(bp + comp + 4 * w4);
            Qt[dq + 4*w4 + 0][row] = fmaf(sgn * xb.x, s4.x, xa.x * c4.x);
            Qt[dq + 4*w4 + 1][row] = fmaf(sgn * xb.y, s4.y, xa.y * c4.y);
            Qt[dq + 4*w4 + 2][row] = fmaf(sgn * xb.z, s4.z, xa.z * c4.z);
            Qt[dq + 4*w4 + 3][row] = fmaf(sgn * xb.w, s4.w, xa.w * c4.w);
        }
    }
    if (tid < 64) { m_s[tid] = -1e30f; l_s[tid] = 0.f; }
    float O[4][4];
#pragma unroll
    for (int i = 0; i < 4; i++)
#pragma unroll
        for (int j = 0; j < 4; j++) O[i][j] = 0.f;

    for (int c = 0; c < 12; c++) {
        const int kp0 = (w - 1) * 256 + c * 64;
        if (kp0 < 0 || kp0 >= 8192) continue;    // look_around pad (block-uniform)
        {   // stage K chunk (RoPE, transposed) and V chunk
            const int kpos = kp0 + row;
            const float* bp = Kb + kpos * 64;
            const float* cp = cosT + kpos * 32 + e;
            const float* sp = sinT + kpos * 32 + e;
#pragma unroll
            for (int w4 = 0; w4 < 4; w4++) {
                float4 c4 = *(const float4*)(cp + 4 * w4);
                float4 s4 = *(const float4*)(sp + 4 * w4);
                float4 xa = *(const float4*)(bp + dq + 4 * w4);
                float4 xb = *(const float4*)(bp + comp + 4 * w4);
                KtP[dq + 4*w4 + 0][row] = fmaf(sgn * xb.x, s4.x, xa.x * c4.x);
                KtP[dq + 4*w4 + 1][row] = fmaf(sgn * xb.y, s4.y, xa.y * c4.y);
                KtP[dq + 4*w4 + 2][row] = fmaf(sgn * xb.z, s4.z, xa.z * c4.z);
                KtP[dq + 4*w4 + 3][row] = fmaf(sgn * xb.w, s4.w, xa.w * c4.w);
                *(float4*)&Vs[row][dq + 4 * w4] = *(const float4*)(Vb + kpos * 64 + dq + 4 * w4);
            }
        }
        if (tid < 64) { rmax_s[tid] = 0u; lsum_s[tid] = 0.f; }
        __syncthreads();
        // S = (Qr @ Kr^T) * d^-0.5  -- 4x4 per thread
        float s[4][4];
#pragma unroll
        for (int i = 0; i < 4; i++)
#pragma unroll
            for (int j = 0; j < 4; j++) s[i][j] = 0.f;
#pragma unroll 8
        for (int kk = 0; kk < 64; kk++) {
            float4 a4 = *(float4*)&Qt[kk][ty * 4];
            float4 b4 = *(float4*)&KtP[kk][tx * 4];
            float a[4] = {a4.x, a4.y, a4.z, a4.w};
            float bb[4] = {b4.x, b4.y, b4.z, b4.w};
#pragma unroll
            for (int i = 0; i < 4; i++)
#pragma unroll
                for (int j = 0; j < 4; j++) s[i][j] = fmaf(a[i], bb[j], s[i][j]);
        }
#pragma unroll
        for (int i = 0; i < 4; i++) {
            float rm = -1e30f;
#pragma unroll
            for (int j = 0; j < 4; j++) { s[i][j] *= 0.125f; rm = fmaxf(rm, s[i][j]); }
            atomicMax(&rmax_s[ty * 4 + i], encf(rm));
        }
        __syncthreads();          // rmax done; also: all KtP reads done -> safe to alias as pT
        float alpha[4];
#pragma unroll
        for (int i = 0; i < 4; i++) {
            const int r = ty * 4 + i;
            float mold = m_s[r];
            float mn = fmaxf(mold, decf(rmax_s[r]));
            alpha[i] = expf(mold - mn);
            float ps = 0.f;
#pragma unroll
            for (int j = 0; j < 4; j++) { s[i][j] = expf(s[i][j] - mn); ps += s[i][j]; }
            atomicAdd(&lsum_s[r], ps);
        }
#pragma unroll
        for (int j = 0; j < 4; j++)    // pT[k][q], float4 along q
            *(float4*)&KtP[tx * 4 + j][ty * 4] =
                make_float4(s[0][j], s[1][j], s[2][j], s[3][j]);
#pragma unroll
        for (int i = 0; i < 4; i++)
#pragma unroll
            for (int j = 0; j < 4; j++) O[i][j] *= alpha[i];
        __syncthreads();          // pT + lsum complete
        if (tid < 64) {
            float mold = m_s[tid];
            float mn = fmaxf(mold, decf(rmax_s[tid]));
            l_s[tid] = l_s[tid] * expf(mold - mn) + lsum_s[tid];
            m_s[tid] = mn;
        }
        // O += P @ V
#pragma unroll 8
        for (int kk = 0; kk < 64; kk++) {
            float4 a4 = *(float4*)&KtP[kk][ty * 4];
            float4 b4 = *(float4*)&Vs[kk][tx * 4];
            float a[4] = {a4.x, a4.y, a4.z, a4.w};
            float bb[4] = {b4.x, b4.y, b4.z, b4.w};
#pragma unroll
            for (int i = 0; i < 4; i++)
#pragma unroll
                for (int j = 0; j < 4; j++) O[i][j] = fmaf(a[i], bb[j], O[i][j]);
        }
        __syncthreads();          // before next chunk's staging overwrites KtP/Vs
    }
    float* __restrict__ attL = ws + O_ATTL;   // [2][2][8192][64]
#pragma unroll
    for (int i = 0; i < 4; i++) {
        const int q = q0 + ty * 4 + i;
        const float inv = 1.f / fmaxf(l_s[ty * 4 + i], 1e-30f);
        *(float4*)&attL[((b * 2 + lh) * 8192 + q) * 64 + tx * 4] =
            make_float4(O[i][0] * inv, O[i][1] * inv, O[i][2] * inv, O[i][3] * inv);
    }
}

// ---------------- output projection + bias ----------------
__launch_bounds__(256)
__global__ void k_out(const float* __restrict__ Wo,
                      const float* __restrict__ bo,
                      const float* __restrict__ ws,
                      float* __restrict__ out) {
    __shared__ float As[16][128];
    __shared__ float Bs[16][128];
    const float* __restrict__ attG = ws + O_K;      // [16384][384]
    const float* __restrict__ attL = ws + O_ATTL;   // [4][8192][64]
    const int r0 = blockIdx.x * 128, c0 = blockIdx.y * 128;
    const int tid = threadIdx.x, tx = tid & 15, ty = tid >> 4;
    const int am = tid >> 1, ako = (tid & 1) * 8;
    const int bk = tid >> 4, bjo = (tid & 15) * 8;
    float acc[8][8];
#pragma unroll
    for (int i = 0; i < 8; i++)
#pragma unroll
        for (int j = 0; j < 8; j++) acc[i][j] = 0.f;

    for (int k0 = 0; k0 < 512; k0 += 16) {
        const int row = r0 + am;
        float4 a0, a1;
        if (k0 < 384) {
            a0 = *(const float4*)(attG + row * 384 + k0 + ako);
            a1 = *(const float4*)(attG + row * 384 + k0 + ako + 4);
        } else {
            const int bb = row >> 13, nn = row & 8191;
            const int kk0 = k0 + ako - 384;
            const int lhh = kk0 >> 6, dd = kk0 & 63;
            const float* src = attL + ((bb * 2 + lhh) * 8192 + nn) * 64 + dd;
            a0 = *(const float4*)(src);
            a1 = *(const float4*)(src + 4);
        }
        float4 b0 = *(const float4*)(Wo + (k0 + bk) * 512 + c0 + bjo);
        float4 b1 = *(const float4*)(Wo + (k0 + bk) * 512 + c0 + bjo + 4);
        As[ako + 0][am] = a0.x; As[ako + 1][am] = a0.y;
        As[ako + 2][am] = a0.z; As[ako + 3][am] = a0.w;
        As[ako + 4][am] = a1.x; As[ako + 5][am] = a1.y;
        As[ako + 6][am] = a1.z; As[ako + 7][am] = a1.w;
        *(float4*)&Bs[bk][bjo]     = b0;
        *(float4*)&Bs[bk][bjo + 4] = b1;
        __syncthreads();
#pragma unroll
        for (int kk = 0; kk < 16; kk++) {
            float4 a04 = *(float4*)&As[kk][ty * 8];
            float4 a14 = *(float4*)&As[kk][ty * 8 + 4];
            float4 b04 = *(float4*)&Bs[kk][tx * 4];
            float4 b14 = *(float4*)&Bs[kk][64 + tx * 4];
            float a[8] = {a04.x, a04.y, a04.z, a04.w, a14.x, a14.y, a14.z, a14.w};
            float b[8] = {b04.x, b04.y, b04.z, b04.w, b14.x, b14.y, b14.z, b14.w};
#pragma unroll
            for (int i = 0; i < 8; i++)
#pragma unroll
                for (int j = 0; j < 8; j++) acc[i][j] = fmaf(a[i], b[j], acc[i][j]);
        }
        __syncthreads();
    }
    const int col0 = c0 + tx * 4, col1 = c0 + 64 + tx * 4;
    float4 bo0 = *(const float4*)(bo + col0);
    float4 bo1 = *(const float4*)(bo + col1);
#pragma unroll
    for (int i = 0; i < 8; i++) {
        int r = r0 + ty * 8 + i;
        *(float4*)&out[r * 512 + col0] =
            make_float4(acc[i][0] + bo0.x, acc[i][1] + bo0.y, acc[i][2] + bo0.z, acc[i][3] + bo0.w);
        *(float4*)&out[r * 512 + col1] =
            make_float4(acc[i][4] + bo1.x, acc[i][5] + bo1.y, acc[i][6] + bo1.z, acc[i][7] + bo1.w);
    }
}

extern "C" void kernel_launch(void* const* d_in, const int* in_sizes, int n_in,
                              void* d_out, int out_size, void* d_ws, size_t ws_size,
                              hipStream_t stream) {
    const float* x    = (const float*)d_in[0];
    const float* Wq   = (const float*)d_in[1];
    const float* Wk   = (const float*)d_in[2];
    const float* Wv   = (const float*)d_in[3];
    const float* Wo   = (const float*)d_in[4];
    const float* bo   = (const float*)d_in[5];
    const float* proj = (const float*)d_in[6];
    float* ws = (float*)d_ws;
    float* out = (float*)d_out;

    hipMemsetAsync(d_ws, 0, (size_t)O_ZEND * 4, stream);                 // kmax/ksum/ctx
    hipLaunchKernelGGL(k_rope, dim3(1024), dim3(256), 0, stream, ws);
    hipLaunchKernelGGL(k_qkv,  dim3(128, 4, 3), dim3(256), 0, stream, x, Wq, Wk, Wv, ws);
    hipLaunchKernelGGL(k_kmax, dim3(12, 128), dim3(256), 0, stream, proj, ws);
    hipLaunchKernelGGL(k_kctx, dim3(12, 32), dim3(256), 0, stream, proj, ws);
    hipLaunchKernelGGL(k_local, dim3(4, 128), dim3(256), 0, stream, ws);    // before k_qout!
    hipLaunchKernelGGL(k_qout, dim3(12, 128), dim3(256), 0, stream, proj, ws);
    hipLaunchKernelGGL(k_out,  dim3(128, 4), dim3(256), 0, stream, Wo, bo, ws, out);
}

// Round 5
// 1024.760 us; speedup vs baseline: 1.7511x; 1.0460x over previous
//
#include <hip/hip_runtime.h>

// ---------------- constants ----------------
#define NTOK 8192
#define NORMC 0.35355339059327373f   // 64^-0.25
#define RATIO 0.0625f                // 256^-0.5
#define KEPS  1e-4f

// ws offsets in 4-byte elements  (total 27987008 ele = 106.8 MB)
#define O_KMAX 0                      // 12 x u32 (encoded max)
#define O_KSUM 64                     // 12*256 f32
#define O_CTX  3136                   // 12*256*64 f32
#define O_ZEND 199744                 // zeroed region end
#define O_COS  199744                 // 8192*32
#define O_SIN  461888                 // 8192*32
#define O_Q    724032                 // 2*8*8192*64
#define O_K    9112640                // K; later reused as attG [16384][384]
#define O_V    17501248
#define O_ATTL 25889856               // 2*2*8192*64 (local heads out)
// end: 27987008

__device__ __forceinline__ unsigned encf(float f) {
    unsigned u = __float_as_uint(f);
    return (u & 0x80000000u) ? ~u : (u | 0x80000000u);
}
__device__ __forceinline__ float decf(unsigned u) {
    return (u & 0x80000000u) ? __uint_as_float(u & 0x7fffffffu) : __uint_as_float(~u);
}

// ---------------- RoPE tables (double precision angles) ----------------
__global__ void k_rope(float* __restrict__ ws) {
    int idx = blockIdx.x * 256 + threadIdx.x;      // 8192*32
    int t = idx >> 5, i = idx & 31;
    double invf = pow(10000.0, -(double)(2 * i) / 64.0);
    double ang = (double)t * invf;
    ws[O_COS + idx] = (float)cos(ang);
    ws[O_SIN + idx] = (float)sin(ang);
}

// ---------------- QKV projection: (16384x512)@(512x512) x3 ----------------
__launch_bounds__(256)
__global__ void k_qkv(const float* __restrict__ x,
                      const float* __restrict__ Wq,
                      const float* __restrict__ Wk,
                      const float* __restrict__ Wv,
                      float* __restrict__ ws) {
    __shared__ float As[16][128];   // [k][m]
    __shared__ float Bs[16][128];   // [k][n]
    const int z = blockIdx.z;
    const float* __restrict__ W = (z == 0) ? Wq : ((z == 1) ? Wk : Wv);
    float* __restrict__ out = ws + ((z == 0) ? O_Q : ((z == 1) ? O_K : O_V));
    const int r0 = blockIdx.x * 128, c0 = blockIdx.y * 128;
    const int tid = threadIdx.x, tx = tid & 15, ty = tid >> 4;
    const int am = tid >> 1, ako = (tid & 1) * 8;
    const int bk = tid >> 4, bjo = (tid & 15) * 8;
    float acc[8][8];
#pragma unroll
    for (int i = 0; i < 8; i++)
#pragma unroll
        for (int j = 0; j < 8; j++) acc[i][j] = 0.f;

    for (int k0 = 0; k0 < 512; k0 += 16) {
        float4 a0 = *(const float4*)(x + (r0 + am) * 512 + k0 + ako);
        float4 a1 = *(const float4*)(x + (r0 + am) * 512 + k0 + ako + 4);
        float4 b0 = *(const float4*)(W + (k0 + bk) * 512 + c0 + bjo);
        float4 b1 = *(const float4*)(W + (k0 + bk) * 512 + c0 + bjo + 4);
        As[ako + 0][am] = a0.x; As[ako + 1][am] = a0.y;
        As[ako + 2][am] = a0.z; As[ako + 3][am] = a0.w;
        As[ako + 4][am] = a1.x; As[ako + 5][am] = a1.y;
        As[ako + 6][am] = a1.z; As[ako + 7][am] = a1.w;
        *(float4*)&Bs[bk][bjo]     = b0;
        *(float4*)&Bs[bk][bjo + 4] = b1;
        __syncthreads();
#pragma unroll
        for (int kk = 0; kk < 16; kk++) {
            float4 a04 = *(float4*)&As[kk][ty * 8];
            float4 a14 = *(float4*)&As[kk][ty * 8 + 4];
            float4 b04 = *(float4*)&Bs[kk][tx * 4];
            float4 b14 = *(float4*)&Bs[kk][64 + tx * 4];
            float a[8] = {a04.x, a04.y, a04.z, a04.w, a14.x, a14.y, a14.z, a14.w};
            float b[8] = {b04.x, b04.y, b04.z, b04.w, b14.x, b14.y, b14.z, b14.w};
#pragma unroll
            for (int i = 0; i < 8; i++)
#pragma unroll
                for (int j = 0; j < 8; j++) acc[i][j] = fmaf(a[i], b[j], acc[i][j]);
        }
        __syncthreads();
    }
    const int bi = r0 >> 13;
#pragma unroll
    for (int i = 0; i < 8; i++) {
        int n = (r0 + ty * 8 + i) & 8191;
        int col0 = c0 + tx * 4;
        int h0 = col0 >> 6, d0 = col0 & 63;
        *(float4*)&out[((bi * 8 + h0) * 8192 + n) * 64 + d0] =
            make_float4(acc[i][0], acc[i][1], acc[i][2], acc[i][3]);
        int col1 = c0 + 64 + tx * 4;
        int h1 = col1 >> 6, d1 = col1 & 63;
        *(float4*)&out[((bi * 8 + h1) * 8192 + n) * 64 + d1] =
            make_float4(acc[i][4], acc[i][5], acc[i][6], acc[i][7]);
    }
}

// ---------------- key-side global max of dd = norm*(K.projT) ----------------
__launch_bounds__(256)
__global__ void k_kmax(const float* __restrict__ proj, float* __restrict__ ws) {
    __shared__ float As[16][64];     // [d][n]
    __shared__ float Bs[16][256];    // [d][j]
    __shared__ unsigned bmax;
    const int bh = blockIdx.x, b = bh / 6, h = bh % 6;
    const float* __restrict__ Kp = ws + O_K + (b * 8 + h) * 8192 * 64;
    const int n0 = blockIdx.y * 64;
    const int tid = threadIdx.x, tx = tid & 15, ty = tid >> 4;
    if (tid == 0) bmax = 0u;
    const int an = tid >> 2, adq = (tid & 3) * 4;
    float acc[4][16];
#pragma unroll
    for (int i = 0; i < 4; i++)
#pragma unroll
        for (int j = 0; j < 16; j++) acc[i][j] = 0.f;

    for (int k0 = 0; k0 < 64; k0 += 16) {
        float4 va = *(const float4*)(Kp + (n0 + an) * 64 + k0 + adq);
        float fp[16];
#pragma unroll
        for (int q = 0; q < 4; q++) {
            float4 p = *(const float4*)(proj + tid * 64 + k0 + q * 4);
            fp[q*4+0] = p.x; fp[q*4+1] = p.y; fp[q*4+2] = p.z; fp[q*4+3] = p.w;
        }
        As[adq + 0][an] = va.x; As[adq + 1][an] = va.y;
        As[adq + 2][an] = va.z; As[adq + 3][an] = va.w;
#pragma unroll
        for (int l = 0; l < 16; l++) Bs[l][tid] = fp[l];
        __syncthreads();
#pragma unroll
        for (int kk = 0; kk < 16; kk++) {
            float4 a4 = *(float4*)&As[kk][ty * 4];
            float a[4] = {a4.x, a4.y, a4.z, a4.w};
#pragma unroll
            for (int g = 0; g < 4; g++) {
                float4 b4 = *(float4*)&Bs[kk][g * 64 + tx * 4];
                float bb[4] = {b4.x, b4.y, b4.z, b4.w};
#pragma unroll
                for (int i = 0; i < 4; i++)
#pragma unroll
                    for (int j = 0; j < 4; j++)
                        acc[i][g * 4 + j] = fmaf(a[i], bb[j], acc[i][g * 4 + j]);
            }
        }
        __syncthreads();
    }
    float m = acc[0][0];
#pragma unroll
    for (int i = 0; i < 4; i++)
#pragma unroll
        for (int j = 0; j < 16; j++) m = fmaxf(m, acc[i][j]);
    atomicMax(&bmax, encf(m * NORMC));
    __syncthreads();
    if (tid == 0) atomicMax((unsigned*)ws + O_KMAX + bh, bmax);
}

// ---------------- key-side: kp, k_sum, ctx = kp^T @ V ----------------
// Occupancy rewrite: grid (12, 64), 128 rows/block, j in 64-chunks.
// LDS 52.5 KB -> 3 blocks/CU (was 60.4 KB / grid 384 -> ~1.5 blocks/CU).
__launch_bounds__(256, 3)
__global__ void k_kctx(const float* __restrict__ proj, float* __restrict__ ws) {
    __shared__ float Kt[64][68];     // K tile transposed [d][n]
    __shared__ float PV[64][68];     // phase1: proj^T [d][j]; phase2: V [n][d]
    __shared__ float kps[64][68];    // kp tile [n][j]
    __shared__ float diag_s[128];
    __shared__ float ksum_s[256];
    const int bh = blockIdx.x, b = bh / 6, h = bh % 6;
    const int n0 = blockIdx.y * 128;
    const float* __restrict__ Kp = ws + O_K + (b * 8 + h) * 8192 * 64;
    const float* __restrict__ Vp = ws + O_V + (b * 8 + h) * 8192 * 64;
    const float kmax = decf(((const unsigned*)ws)[O_KMAX + bh]);
    const int tid = threadIdx.x, tx = tid & 15, ty = tid >> 4;
    const int row = tid >> 2, dq = (tid & 3) * 16;   // staging role
    ksum_s[tid] = 0.f;

    for (int jq = 0; jq < 4; jq++) {
        float acc2[4][4];
#pragma unroll
        for (int i = 0; i < 4; i++)
#pragma unroll
            for (int j = 0; j < 4; j++) acc2[i][j] = 0.f;

        for (int sub = 0; sub < 2; sub++) {
            const int n0s = n0 + sub * 64;
            {   // stage Kt (transposed) + Pt (transposed)
                const float* bp = Kp + (n0s + row) * 64 + dq;
                const float* pp = proj + (jq * 64 + row) * 64 + dq;
#pragma unroll
                for (int q = 0; q < 4; q++) {
                    float4 v = *(const float4*)(bp + 4 * q);
                    Kt[dq + 4*q + 0][row] = v.x; Kt[dq + 4*q + 1][row] = v.y;
                    Kt[dq + 4*q + 2][row] = v.z; Kt[dq + 4*q + 3][row] = v.w;
                    float4 p = *(const float4*)(pp + 4 * q);
                    PV[dq + 4*q + 0][row] = p.x; PV[dq + 4*q + 1][row] = p.y;
                    PV[dq + 4*q + 2][row] = p.z; PV[dq + 4*q + 3][row] = p.w;
                }
            }
            __syncthreads();                             // A: tiles ready
            if (jq == 0 && tid < 64) {                   // diag once per sub
                float ssum = 0.f;
#pragma unroll
                for (int kk = 0; kk < 64; kk++) { float v = Kt[kk][tid]; ssum = fmaf(v, v, ssum); }
                diag_s[sub * 64 + tid] = ssum;
            }
            // phase1: dd[n][j] = K . P^T  (4x4/thread)
            float s[4][4];
#pragma unroll
            for (int i = 0; i < 4; i++)
#pragma unroll
                for (int j = 0; j < 4; j++) s[i][j] = 0.f;
#pragma unroll 8
            for (int kk = 0; kk < 64; kk++) {
                float4 a4 = *(float4*)&Kt[kk][ty * 4];
                float4 b4 = *(float4*)&PV[kk][tx * 4];
                float a[4] = {a4.x, a4.y, a4.z, a4.w};
                float bb[4] = {b4.x, b4.y, b4.z, b4.w};
#pragma unroll
                for (int i = 0; i < 4; i++)
#pragma unroll
                    for (int j = 0; j < 4; j++) s[i][j] = fmaf(a[i], bb[j], s[i][j]);
            }
            if (jq == 0) __syncthreads();                // A2: diag_s visible
            // exp -> kp, kps write, ksum partials
#pragma unroll
            for (int i = 0; i < 4; i++) {
                const float dg = diag_s[sub * 64 + ty * 4 + i] * 0.0625f;
#pragma unroll
                for (int j = 0; j < 4; j++)
                    s[i][j] = RATIO * (expf(fminf(NORMC * s[i][j] - dg - kmax, 0.f)) + KEPS);
                *(float4*)&kps[ty * 4 + i][tx * 4] = make_float4(s[i][0], s[i][1], s[i][2], s[i][3]);
            }
#pragma unroll
            for (int j = 0; j < 4; j++)
                atomicAdd(&ksum_s[jq * 64 + tx * 4 + j],
                          s[0][j] + s[1][j] + s[2][j] + s[3][j]);
            __syncthreads();                             // B: kps ready, PV phase1 done
            {   // stage V over PV
                const float* vp = Vp + (n0s + row) * 64 + dq;
#pragma unroll
                for (int q = 0; q < 4; q++)
                    *(float4*)&PV[row][dq + 4 * q] = *(const float4*)(vp + 4 * q);
            }
            __syncthreads();                             // C: V ready
            // phase2: ctx[j][d] += kp^T @ V  (4x4/thread)
#pragma unroll 8
            for (int kk = 0; kk < 64; kk++) {
                float4 a4 = *(float4*)&kps[kk][ty * 4];
                float4 b4 = *(float4*)&PV[kk][tx * 4];
                float a[4] = {a4.x, a4.y, a4.z, a4.w};
                float bb[4] = {b4.x, b4.y, b4.z, b4.w};
#pragma unroll
                for (int i = 0; i < 4; i++)
#pragma unroll
                    for (int j = 0; j < 4; j++) acc2[i][j] = fmaf(a[i], bb[j], acc2[i][j]);
            }
            __syncthreads();                             // D: before next staging
        }
        // flush ctx partial for this j-chunk
        float* __restrict__ ctxp = ws + O_CTX + bh * 16384;
#pragma unroll
        for (int i = 0; i < 4; i++)
#pragma unroll
            for (int j = 0; j < 4; j++)
                atomicAdd(&ctxp[(jq * 64 + ty * 4 + i) * 64 + tx * 4 + j], acc2[i][j]);
    }
    atomicAdd(ws + O_KSUM + bh * 256 + tid, ksum_s[tid]);
}

// ---------------- query-side: dd, rowmax, qp, attG = qp.ctx / (qp.ksum) ----------------
// writes into the (dead) K region, stride 384
__launch_bounds__(256)
__global__ void k_qout(const float* __restrict__ proj, float* __restrict__ ws) {
    __shared__ float As1[16][64];
    __shared__ float Bs1[16][256];
    __shared__ float qps[64][68];    // qp [n][j-chunk]
    __shared__ float Bs2[64][68];    // ctx chunk [j][d]
    __shared__ float ksum_s[256];
    __shared__ unsigned rmax[64];
    __shared__ float diag_s[64];
    __shared__ float denom_s[64];
    const int bh = blockIdx.x, b = bh / 6, h = bh % 6;
    const int n0 = blockIdx.y * 64;
    const float* __restrict__ Qp = ws + O_Q + (b * 8 + h) * 8192 * 64;
    const float* __restrict__ ctxp = ws + O_CTX + bh * 16384;
    float* __restrict__ attG = ws + O_K;     // [16384][384]
    const int tid = threadIdx.x, tx = tid & 15, ty = tid >> 4;
    if (tid < 64) { rmax[tid] = 0u; diag_s[tid] = 0.f; denom_s[tid] = 0.f; }
    ksum_s[tid] = ws[O_KSUM + bh * 256 + tid];
    float acc1[4][16];
#pragma unroll
    for (int i = 0; i < 4; i++)
#pragma unroll
        for (int j = 0; j < 16; j++) acc1[i][j] = 0.f;
    const int an = tid >> 2, adq = (tid & 3) * 4;

    for (int kt = 0; kt < 4; kt++) {
        const int k0 = kt * 16;
        float4 va = *(const float4*)(Qp + (n0 + an) * 64 + k0 + adq);
        float fp[16];
#pragma unroll
        for (int q = 0; q < 4; q++) {
            float4 p = *(const float4*)(proj + tid * 64 + k0 + q * 4);
            fp[q*4+0] = p.x; fp[q*4+1] = p.y; fp[q*4+2] = p.z; fp[q*4+3] = p.w;
        }
        As1[adq + 0][an] = va.x; As1[adq + 1][an] = va.y;
        As1[adq + 2][an] = va.z; As1[adq + 3][an] = va.w;
#pragma unroll
        for (int l = 0; l < 16; l++) Bs1[l][tid] = fp[l];
        __syncthreads();
        if (tid < 64) {
            float s = diag_s[tid];
#pragma unroll
            for (int kk = 0; kk < 16; kk++) { float v = As1[kk][tid]; s = fmaf(v, v, s); }
            diag_s[tid] = s;
        }
#pragma unroll
        for (int kk = 0; kk < 16; kk++) {
            float4 a4 = *(float4*)&As1[kk][ty * 4];
            float a[4] = {a4.x, a4.y, a4.z, a4.w};
#pragma unroll
            for (int g = 0; g < 4; g++) {
                float4 b4 = *(float4*)&Bs1[kk][g * 64 + tx * 4];
                float bb[4] = {b4.x, b4.y, b4.z, b4.w};
#pragma unroll
                for (int i = 0; i < 4; i++)
#pragma unroll
                    for (int j = 0; j < 4; j++)
                        acc1[i][g * 4 + j] = fmaf(a[i], bb[j], acc1[i][g * 4 + j]);
            }
        }
        __syncthreads();
    }
#pragma unroll
    for (int i = 0; i < 4; i++) {
        float m = acc1[i][0];
#pragma unroll
        for (int c = 1; c < 16; c++) m = fmaxf(m, acc1[i][c]);
        atomicMax(&rmax[ty * 4 + i], encf(m * NORMC));
    }
    __syncthreads();
    float rmx[4], dg[4];
#pragma unroll
    for (int i = 0; i < 4; i++) {
        rmx[i] = decf(rmax[ty * 4 + i]);
        dg[i] = diag_s[ty * 4 + i] * 0.0625f;
    }
    float acc2[4][4];
#pragma unroll
    for (int i = 0; i < 4; i++)
#pragma unroll
        for (int j = 0; j < 4; j++) acc2[i][j] = 0.f;

    for (int jc = 0; jc < 4; jc++) {
#pragma unroll
        for (int i = 0; i < 4; i++) {
            float q0 = RATIO * (expf(fminf(NORMC * acc1[i][jc * 4 + 0] - dg[i] - rmx[i], 0.f)) + KEPS);
            float q1 = RATIO * (expf(fminf(NORMC * acc1[i][jc * 4 + 1] - dg[i] - rmx[i], 0.f)) + KEPS);
            float q2 = RATIO * (expf(fminf(NORMC * acc1[i][jc * 4 + 2] - dg[i] - rmx[i], 0.f)) + KEPS);
            float q3 = RATIO * (expf(fminf(NORMC * acc1[i][jc * 4 + 3] - dg[i] - rmx[i], 0.f)) + KEPS);
            *(float4*)&qps[ty * 4 + i][tx * 4] = make_float4(q0, q1, q2, q3);
            float ds = q0 * ksum_s[jc * 64 + tx * 4 + 0] + q1 * ksum_s[jc * 64 + tx * 4 + 1]
                     + q2 * ksum_s[jc * 64 + tx * 4 + 2] + q3 * ksum_s[jc * 64 + tx * 4 + 3];
            atomicAdd(&denom_s[ty * 4 + i], ds);
        }
        {   // stage ctx chunk
            const int ck = tid >> 2, cdq = (tid & 3) * 16;
#pragma unroll
            for (int wv = 0; wv < 4; wv++) {
                float4 v = *(const float4*)(ctxp + (jc * 64 + ck) * 64 + cdq + 4 * wv);
                *(float4*)&Bs2[ck][cdq + 4 * wv] = v;
            }
        }
        __syncthreads();
#pragma unroll 8
        for (int kk = 0; kk < 64; kk++) {
            float a[4] = {qps[ty * 4 + 0][kk], qps[ty * 4 + 1][kk],
                          qps[ty * 4 + 2][kk], qps[ty * 4 + 3][kk]};
            float4 b4 = *(float4*)&Bs2[kk][tx * 4];
            float bb[4] = {b4.x, b4.y, b4.z, b4.w};
#pragma unroll
            for (int i = 0; i < 4; i++)
#pragma unroll
                for (int j = 0; j < 4; j++) acc2[i][j] = fmaf(a[i], bb[j], acc2[i][j]);
        }
        __syncthreads();
    }
#pragma unroll
    for (int i = 0; i < 4; i++) {
        int n = n0 + ty * 4 + i;
        float inv = 1.0f / fmaxf(denom_s[ty * 4 + i], 1e-30f);
        *(float4*)&attG[(b * 8192 + n) * 384 + h * 64 + tx * 4] =
            make_float4(acc2[i][0] * inv, acc2[i][1] * inv, acc2[i][2] * inv, acc2[i][3] * inv);
    }
}

// ---------------- local windowed attention w/ RoPE, heads 6..7 ----------------
// Flash-tile: block = 64 queries x 256 threads, 4x4 register GEMMs.
// Runs BEFORE k_qout (which overwrites the K region).
__launch_bounds__(256)
__global__ void k_local(float* __restrict__ ws) {
    __shared__ float Qt[64][64];     // RoPE'd Q, [d][q]
    __shared__ float KtP[64][68];    // RoPE'd K [d][k]; after rowmax barrier reused as pT [k][q]
    __shared__ float Vs[64][68];     // V chunk [k][d]
    __shared__ unsigned rmax_s[64];
    __shared__ float m_s[64], l_s[64], lsum_s[64];
    const int bhp = blockIdx.x, b = bhp >> 1, lh = bhp & 1, h = 6 + lh;
    const int tile = blockIdx.y;                 // 0..127 (64-query tiles)
    const int w = tile >> 2;                     // window index
    const int q0 = tile * 64;
    const float* __restrict__ Qb = ws + O_Q + (b * 8 + h) * 8192 * 64;
    const float* __restrict__ Kb = ws + O_K + (b * 8 + h) * 8192 * 64;
    const float* __restrict__ Vb = ws + O_V + (b * 8 + h) * 8192 * 64;
    const float* __restrict__ cosT = ws + O_COS;
    const float* __restrict__ sinT = ws + O_SIN;
    const int tid = threadIdx.x, tx = tid & 15, ty = tid >> 4;
    const int row = tid >> 2, dq = (tid & 3) * 16;   // staging: 4 threads x 16 dims per row
    const int e = dq & 31;
    const int comp = (dq < 32) ? dq + 32 : dq - 32;
    const float sgn = (dq < 32) ? -1.f : 1.f;

    {   // stage Q tile with RoPE, transposed [d][q]
        const int qpos = q0 + row;
        const float* bp = Qb + qpos * 64;
        const float* cp = cosT + qpos * 32 + e;
        const float* sp = sinT + qpos * 32 + e;
#pragma unroll
        for (int w4 = 0; w4 < 4; w4++) {
            float4 c4 = *(const float4*)(cp + 4 * w4);
            float4 s4 = *(const float4*)(sp + 4 * w4);
            float4 xa = *(const float4*)(bp + dq + 4 * w4);
            float4 xb = *(const float4*)(bp + comp + 4 * w4);
            Qt[dq + 4*w4 + 0][row] = fmaf(sgn * xb.x, s4.x, xa.x * c4.x);
            Qt[dq + 4*w4 + 1][row] = fmaf(sgn * xb.y, s4.y, xa.y * c4.y);
            Qt[dq + 4*w4 + 2][row] = fmaf(sgn * xb.z, s4.z, xa.z * c4.z);
            Qt[dq + 4*w4 + 3][row] = fmaf(sgn * xb.w, s4.w, xa.w * c4.w);
        }
    }
    if (tid < 64) { m_s[tid] = -1e30f; l_s[tid] = 0.f; }
    float O[4][4];
#pragma unroll
    for (int i = 0; i < 4; i++)
#pragma unroll
        for (int j = 0; j < 4; j++) O[i][j] = 0.f;

    for (int c = 0; c < 12; c++) {
        const int kp0 = (w - 1) * 256 + c * 64;
        if (kp0 < 0 || kp0 >= 8192) continue;    // look_around pad (block-uniform)
        {   // stage K chunk (RoPE, transposed) and V chunk
            const int kpos = kp0 + row;
            const float* bp = Kb + kpos * 64;
            const float* cp = cosT + kpos * 32 + e;
            const float* sp = sinT + kpos * 32 + e;
#pragma unroll
            for (int w4 = 0; w4 < 4; w4++) {
                float4 c4 = *(const float4*)(cp + 4 * w4);
                float4 s4 = *(const float4*)(sp + 4 * w4);
                float4 xa = *(const float4*)(bp + dq + 4 * w4);
                float4 xb = *(const float4*)(bp + comp + 4 * w4);
                KtP[dq + 4*w4 + 0][row] = fmaf(sgn * xb.x, s4.x, xa.x * c4.x);
                KtP[dq + 4*w4 + 1][row] = fmaf(sgn * xb.y, s4.y, xa.y * c4.y);
                KtP[dq + 4*w4 + 2][row] = fmaf(sgn * xb.z, s4.z, xa.z * c4.z);
                KtP[dq + 4*w4 + 3][row] = fmaf(sgn * xb.w, s4.w, xa.w * c4.w);
                *(float4*)&Vs[row][dq + 4 * w4] = *(const float4*)(Vb + kpos * 64 + dq + 4 * w4);
            }
        }
        if (tid < 64) { rmax_s[tid] = 0u; lsum_s[tid] = 0.f; }
        __syncthreads();
        // S = (Qr @ Kr^T) * d^-0.5  -- 4x4 per thread
        float s[4][4];
#pragma unroll
        for (int i = 0; i < 4; i++)
#pragma unroll
            for (int j = 0; j < 4; j++) s[i][j] = 0.f;
#pragma unroll 8
        for (int kk = 0; kk < 64; kk++) {
            float4 a4 = *(float4*)&Qt[kk][ty * 4];
            float4 b4 = *(float4*)&KtP[kk][tx * 4];
            float a[4] = {a4.x, a4.y, a4.z, a4.w};
            float bb[4] = {b4.x, b4.y, b4.z, b4.w};
#pragma unroll
            for (int i = 0; i < 4; i++)
#pragma unroll
                for (int j = 0; j < 4; j++) s[i][j] = fmaf(a[i], bb[j], s[i][j]);
        }
#pragma unroll
        for (int i = 0; i < 4; i++) {
            float rm = -1e30f;
#pragma unroll
            for (int j = 0; j < 4; j++) { s[i][j] *= 0.125f; rm = fmaxf(rm, s[i][j]); }
            atomicMax(&rmax_s[ty * 4 + i], encf(rm));
        }
        __syncthreads();          // rmax done; also: all KtP reads done -> safe to alias as pT
        float alpha[4];
#pragma unroll
        for (int i = 0; i < 4; i++) {
            const int r = ty * 4 + i;
            float mold = m_s[r];
            float mn = fmaxf(mold, decf(rmax_s[r]));
            alpha[i] = expf(mold - mn);
            float ps = 0.f;
#pragma unroll
            for (int j = 0; j < 4; j++) { s[i][j] = expf(s[i][j] - mn); ps += s[i][j]; }
            atomicAdd(&lsum_s[r], ps);
        }
#pragma unroll
        for (int j = 0; j < 4; j++)    // pT[k][q], float4 along q
            *(float4*)&KtP[tx * 4 + j][ty * 4] =
                make_float4(s[0][j], s[1][j], s[2][j], s[3][j]);
#pragma unroll
        for (int i = 0; i < 4; i++)
#pragma unroll
            for (int j = 0; j < 4; j++) O[i][j] *= alpha[i];
        __syncthreads();          // pT + lsum complete
        if (tid < 64) {
            float mold = m_s[tid];
            float mn = fmaxf(mold, decf(rmax_s[tid]));
            l_s[tid] = l_s[tid] * expf(mold - mn) + lsum_s[tid];
            m_s[tid] = mn;
        }
        // O += P @ V
#pragma unroll 8
        for (int kk = 0; kk < 64; kk++) {
            float4 a4 = *(float4*)&KtP[kk][ty * 4];
            float4 b4 = *(float4*)&Vs[kk][tx * 4];
            float a[4] = {a4.x, a4.y, a4.z, a4.w};
            float bb[4] = {b4.x, b4.y, b4.z, b4.w};
#pragma unroll
            for (int i = 0; i < 4; i++)
#pragma unroll
                for (int j = 0; j < 4; j++) O[i][j] = fmaf(a[i], bb[j], O[i][j]);
        }
        __syncthreads();          // before next chunk's staging overwrites KtP/Vs
    }
    float* __restrict__ attL = ws + O_ATTL;   // [2][2][8192][64]
#pragma unroll
    for (int i = 0; i < 4; i++) {
        const int q = q0 + ty * 4 + i;
        const float inv = 1.f / fmaxf(l_s[ty * 4 + i], 1e-30f);
        *(float4*)&attL[((b * 2 + lh) * 8192 + q) * 64 + tx * 4] =
            make_float4(O[i][0] * inv, O[i][1] * inv, O[i][2] * inv, O[i][3] * inv);
    }
}

// ---------------- output projection + bias ----------------
__launch_bounds__(256)
__global__ void k_out(const float* __restrict__ Wo,
                      const float* __restrict__ bo,
                      const float* __restrict__ ws,
                      float* __restrict__ out) {
    __shared__ float As[16][128];
    __shared__ float Bs[16][128];
    const float* __restrict__ attG = ws + O_K;      // [16384][384]
    const float* __restrict__ attL = ws + O_ATTL;   // [4][8192][64]
    const int r0 = blockIdx.x * 128, c0 = blockIdx.y * 128;
    const int tid = threadIdx.x, tx = tid & 15, ty = tid >> 4;
    const int am = tid >> 1, ako = (tid & 1) * 8;
    const int bk = tid >> 4, bjo = (tid & 15) * 8;
    float acc[8][8];
#pragma unroll
    for (int i = 0; i < 8; i++)
#pragma unroll
        for (int j = 0; j < 8; j++) acc[i][j] = 0.f;

    for (int k0 = 0; k0 < 512; k0 += 16) {
        const int row = r0 + am;
        float4 a0, a1;
        if (k0 < 384) {
            a0 = *(const float4*)(attG + row * 384 + k0 + ako);
            a1 = *(const float4*)(attG + row * 384 + k0 + ako + 4);
        } else {
            const int bb = row >> 13, nn = row & 8191;
            const int kk0 = k0 + ako - 384;
            const int lhh = kk0 >> 6, dd = kk0 & 63;
            const float* src = attL + ((bb * 2 + lhh) * 8192 + nn) * 64 + dd;
            a0 = *(const float4*)(src);
            a1 = *(const float4*)(src + 4);
        }
        float4 b0 = *(const float4*)(Wo + (k0 + bk) * 512 + c0 + bjo);
        float4 b1 = *(const float4*)(Wo + (k0 + bk) * 512 + c0 + bjo + 4);
        As[ako + 0][am] = a0.x; As[ako + 1][am] = a0.y;
        As[ako + 2][am] = a0.z; As[ako + 3][am] = a0.w;
        As[ako + 4][am] = a1.x; As[ako + 5][am] = a1.y;
        As[ako + 6][am] = a1.z; As[ako + 7][am] = a1.w;
        *(float4*)&Bs[bk][bjo]     = b0;
        *(float4*)&Bs[bk][bjo + 4] = b1;
        __syncthreads();
#pragma unroll
        for (int kk = 0; kk < 16; kk++) {
            float4 a04 = *(float4*)&As[kk][ty * 8];
            float4 a14 = *(float4*)&As[kk][ty * 8 + 4];
            float4 b04 = *(float4*)&Bs[kk][tx * 4];
            float4 b14 = *(float4*)&Bs[kk][64 + tx * 4];
            float a[8] = {a04.x, a04.y, a04.z, a04.w, a14.x, a14.y, a14.z, a14.w};
            float b[8] = {b04.x, b04.y, b04.z, b04.w, b14.x, b14.y, b14.z, b14.w};
#pragma unroll
            for (int i = 0; i < 8; i++)
#pragma unroll
                for (int j = 0; j < 8; j++) acc[i][j] = fmaf(a[i], b[j], acc[i][j]);
        }
        __syncthreads();
    }
    const int col0 = c0 + tx * 4, col1 = c0 + 64 + tx * 4;
    float4 bo0 = *(const float4*)(bo + col0);
    float4 bo1 = *(const float4*)(bo + col1);
#pragma unroll
    for (int i = 0; i < 8; i++) {
        int r = r0 + ty * 8 + i;
        *(float4*)&out[r * 512 + col0] =
            make_float4(acc[i][0] + bo0.x, acc[i][1] + bo0.y, acc[i][2] + bo0.z, acc[i][3] + bo0.w);
        *(float4*)&out[r * 512 + col1] =
            make_float4(acc[i][4] + bo1.x, acc[i][5] + bo1.y, acc[i][6] + bo1.z, acc[i][7] + bo1.w);
    }
}

extern "C" void kernel_launch(void* const* d_in, const int* in_sizes, int n_in,
                              void* d_out, int out_size, void* d_ws, size_t ws_size,
                              hipStream_t stream) {
    const float* x    = (const float*)d_in[0];
    const float* Wq   = (const float*)d_in[1];
    const float* Wk   = (const float*)d_in[2];
    const float* Wv   = (const float*)d_in[3];
    const float* Wo   = (const float*)d_in[4];
    const float* bo   = (const float*)d_in[5];
    const float* proj = (const float*)d_in[6];
    float* ws = (float*)d_ws;
    float* out = (float*)d_out;

    hipMemsetAsync(d_ws, 0, (size_t)O_ZEND * 4, stream);                 // kmax/ksum/ctx
    hipLaunchKernelGGL(k_rope, dim3(1024), dim3(256), 0, stream, ws);
    hipLaunchKernelGGL(k_qkv,  dim3(128, 4, 3), dim3(256), 0, stream, x, Wq, Wk, Wv, ws);
    hipLaunchKernelGGL(k_kmax, dim3(12, 128), dim3(256), 0, stream, proj, ws);
    hipLaunchKernelGGL(k_kctx, dim3(12, 64), dim3(256), 0, stream, proj, ws);
    hipLaunchKernelGGL(k_local, dim3(4, 128), dim3(256), 0, stream, ws);    // before k_qout!
    hipLaunchKernelGGL(k_qout, dim3(12, 128), dim3(256), 0, stream, proj, ws);
    hipLaunchKernelGGL(k_out,  dim3(128, 4), dim3(256), 0, stream, Wo, bo, ws, out);
}

// Round 6
// 816.116 us; speedup vs baseline: 2.1987x; 1.2557x over previous
//
#include <hip/hip_runtime.h>

// ---------------- constants ----------------
#define NTOK 8192
#define NORMC 0.35355339059327373f   // 64^-0.25
#define RATIO 0.0625f                // 256^-0.5
#define KEPS  1e-4f

// ws offsets in 4-byte elements  (total 27987008 ele = 106.8 MB)
#define O_KMAX 0                      // 12 x u32 (encoded max)
#define O_KSUM 64                     // 12*256 f32
#define O_CTX  3136                   // 12*256*64 f32
#define O_ZEND 199744                 // zeroed region end
#define O_COS  199744                 // 8192*32
#define O_SIN  461888                 // 8192*32
#define O_Q    724032                 // 2*8*8192*64
#define O_K    9112640                // K; later reused as attG [16384][384]
#define O_V    17501248
#define O_ATTL 25889856               // 2*2*8192*64 (local heads out)
// O_WH: fp16 W^T [3][512][512] lives in the ATTL region (dead until k_local,
// consumed only by k_qkv which runs first) -> zero footprint growth
#define O_WH   25889856
// end: 27987008

typedef _Float16 half8 __attribute__((ext_vector_type(8)));
typedef _Float16 half4h __attribute__((ext_vector_type(4)));
typedef float floatx4 __attribute__((ext_vector_type(4)));

__device__ __forceinline__ unsigned encf(float f) {
    unsigned u = __float_as_uint(f);
    return (u & 0x80000000u) ? ~u : (u | 0x80000000u);
}
__device__ __forceinline__ float decf(unsigned u) {
    return (u & 0x80000000u) ? __uint_as_float(u & 0x7fffffffu) : __uint_as_float(~u);
}

// ---------------- RoPE tables (double precision angles) ----------------
__global__ void k_rope(float* __restrict__ ws) {
    int idx = blockIdx.x * 256 + threadIdx.x;      // 8192*32
    int t = idx >> 5, i = idx & 31;
    double invf = pow(10000.0, -(double)(2 * i) / 64.0);
    double ang = (double)t * invf;
    ws[O_COS + idx] = (float)cos(ang);
    ws[O_SIN + idx] = (float)sin(ang);
}

// ---------------- W -> fp16, transposed to [n][k] ----------------
__launch_bounds__(256)
__global__ void k_half_w(const float* __restrict__ Wq,
                         const float* __restrict__ Wk,
                         const float* __restrict__ Wv,
                         float* __restrict__ ws) {
    __shared__ float T[64][65];
    const int z = blockIdx.z;
    const float* __restrict__ W = (z == 0) ? Wq : ((z == 1) ? Wk : Wv);
    _Float16* __restrict__ Wt = (_Float16*)(ws + O_WH) + (size_t)z * 262144;
    const int k0 = blockIdx.x * 64, n0 = blockIdx.y * 64;
    const int lx = threadIdx.x & 63, ly = threadIdx.x >> 6;   // ly in 0..3
#pragma unroll
    for (int i = 0; i < 16; i++) {
        const int kk = ly * 16 + i;
        T[lx][kk] = W[(k0 + kk) * 512 + n0 + lx];    // T[n-n0][k-k0]
    }
    __syncthreads();
#pragma unroll
    for (int i = 0; i < 16; i++) {
        const int nn = ly * 16 + i;
        Wt[(n0 + nn) * 512 + k0 + lx] = (_Float16)T[nn][lx];
    }
}

// ---------------- QKV projection via fp16 MFMA ----------------
// 128x128 tile, BK=64, x converted fp32->fp16 in staging, W pre-converted/transposed.
// LDS stride 72 halves: frag ds_read_b128 pattern is 2-way (free).
__launch_bounds__(256)
__global__ void k_qkv(const float* __restrict__ x, float* __restrict__ ws) {
    __shared__ _Float16 Ah[128 * 72];
    __shared__ _Float16 Bh[128 * 72];
    const int z = blockIdx.z;
    const _Float16* __restrict__ Wt = (const _Float16*)(ws + O_WH) + (size_t)z * 262144;
    float* __restrict__ out = ws + ((z == 0) ? O_Q : ((z == 1) ? O_K : O_V));
    const int r0 = blockIdx.x * 128, c0 = blockIdx.y * 128;
    const int tid = threadIdx.x;
    const int wv = tid >> 6, lane = tid & 63, lm = lane & 15, lq = lane >> 4;
    const int srow = tid >> 1, skoff = (tid & 1) * 32;
    floatx4 acc[2][8];
#pragma unroll
    for (int m = 0; m < 2; m++)
#pragma unroll
        for (int n = 0; n < 8; n++) acc[m][n] = (floatx4){0.f, 0.f, 0.f, 0.f};

    for (int c = 0; c < 8; c++) {
        const int k0 = c * 64;
        {   // stage A: x fp32 -> fp16 (row-major, k contiguous)
            const float* ap = x + (size_t)(r0 + srow) * 512 + k0 + skoff;
#pragma unroll
            for (int q = 0; q < 4; q++) {
                float4 v0 = *(const float4*)(ap + 8 * q);
                float4 v1 = *(const float4*)(ap + 8 * q + 4);
                half8 h = {(_Float16)v0.x, (_Float16)v0.y, (_Float16)v0.z, (_Float16)v0.w,
                           (_Float16)v1.x, (_Float16)v1.y, (_Float16)v1.z, (_Float16)v1.w};
                *(half8*)&Ah[srow * 72 + skoff + 8 * q] = h;
            }
        }
        {   // stage B: fp16 W^T direct copy
            const _Float16* bp = Wt + (size_t)(c0 + srow) * 512 + k0 + skoff;
#pragma unroll
            for (int q = 0; q < 4; q++)
                *(uint4*)&Bh[srow * 72 + skoff + 8 * q] = *(const uint4*)(bp + 8 * q);
        }
        __syncthreads();
#pragma unroll
        for (int ks = 0; ks < 2; ks++) {
            half8 af[2], bf[8];
            af[0] = *(half8*)&Ah[(wv * 32 + lm) * 72 + ks * 32 + lq * 8];
            af[1] = *(half8*)&Ah[(wv * 32 + 16 + lm) * 72 + ks * 32 + lq * 8];
#pragma unroll
            for (int n = 0; n < 8; n++)
                bf[n] = *(half8*)&Bh[(n * 16 + lm) * 72 + ks * 32 + lq * 8];
#pragma unroll
            for (int m = 0; m < 2; m++)
#pragma unroll
                for (int n = 0; n < 8; n++)
                    acc[m][n] = __builtin_amdgcn_mfma_f32_16x16x32_f16(af[m], bf[n], acc[m][n], 0, 0, 0);
        }
        __syncthreads();
    }
    // epilogue: C/D layout col=lane&15, row=(lane>>4)*4+reg
    const int bi = r0 >> 13;
#pragma unroll
    for (int n = 0; n < 8; n++) {
        const int col = c0 + n * 16 + lm;
        const int h = col >> 6, d = col & 63;
#pragma unroll
        for (int m = 0; m < 2; m++) {
            const int rbase = r0 + wv * 32 + m * 16 + lq * 4;
#pragma unroll
            for (int j = 0; j < 4; j++) {
                const int ng = (rbase + j) & 8191;
                out[((size_t)(bi * 8 + h) * 8192 + ng) * 64 + d] = acc[m][n][j];
            }
        }
    }
}

// ---------------- key-side global max of dd = norm*(K.projT) ----------------
__launch_bounds__(256)
__global__ void k_kmax(const float* __restrict__ proj, float* __restrict__ ws) {
    __shared__ float As[16][64];     // [d][n]
    __shared__ float Bs[16][256];    // [d][j]
    __shared__ unsigned bmax;
    const int bh = blockIdx.x, b = bh / 6, h = bh % 6;
    const float* __restrict__ Kp = ws + O_K + (b * 8 + h) * 8192 * 64;
    const int n0 = blockIdx.y * 64;
    const int tid = threadIdx.x, tx = tid & 15, ty = tid >> 4;
    if (tid == 0) bmax = 0u;
    const int an = tid >> 2, adq = (tid & 3) * 4;
    float acc[4][16];
#pragma unroll
    for (int i = 0; i < 4; i++)
#pragma unroll
        for (int j = 0; j < 16; j++) acc[i][j] = 0.f;

    for (int k0 = 0; k0 < 64; k0 += 16) {
        float4 va = *(const float4*)(Kp + (n0 + an) * 64 + k0 + adq);
        float fp[16];
#pragma unroll
        for (int q = 0; q < 4; q++) {
            float4 p = *(const float4*)(proj + tid * 64 + k0 + q * 4);
            fp[q*4+0] = p.x; fp[q*4+1] = p.y; fp[q*4+2] = p.z; fp[q*4+3] = p.w;
        }
        As[adq + 0][an] = va.x; As[adq + 1][an] = va.y;
        As[adq + 2][an] = va.z; As[adq + 3][an] = va.w;
#pragma unroll
        for (int l = 0; l < 16; l++) Bs[l][tid] = fp[l];
        __syncthreads();
#pragma unroll
        for (int kk = 0; kk < 16; kk++) {
            float4 a4 = *(float4*)&As[kk][ty * 4];
            float a[4] = {a4.x, a4.y, a4.z, a4.w};
#pragma unroll
            for (int g = 0; g < 4; g++) {
                float4 b4 = *(float4*)&Bs[kk][g * 64 + tx * 4];
                float bb[4] = {b4.x, b4.y, b4.z, b4.w};
#pragma unroll
                for (int i = 0; i < 4; i++)
#pragma unroll
                    for (int j = 0; j < 4; j++)
                        acc[i][g * 4 + j] = fmaf(a[i], bb[j], acc[i][g * 4 + j]);
            }
        }
        __syncthreads();
    }
    float m = acc[0][0];
#pragma unroll
    for (int i = 0; i < 4; i++)
#pragma unroll
        for (int j = 0; j < 16; j++) m = fmaxf(m, acc[i][j]);
    atomicMax(&bmax, encf(m * NORMC));
    __syncthreads();
    if (tid == 0) atomicMax((unsigned*)ws + O_KMAX + bh, bmax);
}

// ---------------- key-side: kp, k_sum, ctx = kp^T @ V ----------------
__launch_bounds__(256, 3)
__global__ void k_kctx(const float* __restrict__ proj, float* __restrict__ ws) {
    __shared__ float Kt[64][68];     // K tile transposed [d][n]
    __shared__ float PV[64][68];     // phase1: proj^T [d][j]; phase2: V [n][d]
    __shared__ float kps[64][68];    // kp tile [n][j]
    __shared__ float diag_s[128];
    __shared__ float ksum_s[256];
    const int bh = blockIdx.x, b = bh / 6, h = bh % 6;
    const int n0 = blockIdx.y * 128;
    const float* __restrict__ Kp = ws + O_K + (b * 8 + h) * 8192 * 64;
    const float* __restrict__ Vp = ws + O_V + (b * 8 + h) * 8192 * 64;
    const float kmax = decf(((const unsigned*)ws)[O_KMAX + bh]);
    const int tid = threadIdx.x, tx = tid & 15, ty = tid >> 4;
    const int row = tid >> 2, dq = (tid & 3) * 16;   // staging role
    ksum_s[tid] = 0.f;

    for (int jq = 0; jq < 4; jq++) {
        float acc2[4][4];
#pragma unroll
        for (int i = 0; i < 4; i++)
#pragma unroll
            for (int j = 0; j < 4; j++) acc2[i][j] = 0.f;

        for (int sub = 0; sub < 2; sub++) {
            const int n0s = n0 + sub * 64;
            {   // stage Kt (transposed) + Pt (transposed)
                const float* bp = Kp + (n0s + row) * 64 + dq;
                const float* pp = proj + (jq * 64 + row) * 64 + dq;
#pragma unroll
                for (int q = 0; q < 4; q++) {
                    float4 v = *(const float4*)(bp + 4 * q);
                    Kt[dq + 4*q + 0][row] = v.x; Kt[dq + 4*q + 1][row] = v.y;
                    Kt[dq + 4*q + 2][row] = v.z; Kt[dq + 4*q + 3][row] = v.w;
                    float4 p = *(const float4*)(pp + 4 * q);
                    PV[dq + 4*q + 0][row] = p.x; PV[dq + 4*q + 1][row] = p.y;
                    PV[dq + 4*q + 2][row] = p.z; PV[dq + 4*q + 3][row] = p.w;
                }
            }
            __syncthreads();                             // A: tiles ready
            if (jq == 0 && tid < 64) {                   // diag once per sub
                float ssum = 0.f;
#pragma unroll
                for (int kk = 0; kk < 64; kk++) { float v = Kt[kk][tid]; ssum = fmaf(v, v, ssum); }
                diag_s[sub * 64 + tid] = ssum;
            }
            // phase1: dd[n][j] = K . P^T  (4x4/thread)
            float s[4][4];
#pragma unroll
            for (int i = 0; i < 4; i++)
#pragma unroll
                for (int j = 0; j < 4; j++) s[i][j] = 0.f;
#pragma unroll 8
            for (int kk = 0; kk < 64; kk++) {
                float4 a4 = *(float4*)&Kt[kk][ty * 4];
                float4 b4 = *(float4*)&PV[kk][tx * 4];
                float a[4] = {a4.x, a4.y, a4.z, a4.w};
                float bb[4] = {b4.x, b4.y, b4.z, b4.w};
#pragma unroll
                for (int i = 0; i < 4; i++)
#pragma unroll
                    for (int j = 0; j < 4; j++) s[i][j] = fmaf(a[i], bb[j], s[i][j]);
            }
            if (jq == 0) __syncthreads();                // A2: diag_s visible
#pragma unroll
            for (int i = 0; i < 4; i++) {
                const float dg = diag_s[sub * 64 + ty * 4 + i] * 0.0625f;
#pragma unroll
                for (int j = 0; j < 4; j++)
                    s[i][j] = RATIO * (expf(fminf(NORMC * s[i][j] - dg - kmax, 0.f)) + KEPS);
                *(float4*)&kps[ty * 4 + i][tx * 4] = make_float4(s[i][0], s[i][1], s[i][2], s[i][3]);
            }
#pragma unroll
            for (int j = 0; j < 4; j++)
                atomicAdd(&ksum_s[jq * 64 + tx * 4 + j],
                          s[0][j] + s[1][j] + s[2][j] + s[3][j]);
            __syncthreads();                             // B: kps ready, PV phase1 done
            {   // stage V over PV
                const float* vp = Vp + (n0s + row) * 64 + dq;
#pragma unroll
                for (int q = 0; q < 4; q++)
                    *(float4*)&PV[row][dq + 4 * q] = *(const float4*)(vp + 4 * q);
            }
            __syncthreads();                             // C: V ready
#pragma unroll 8
            for (int kk = 0; kk < 64; kk++) {
                float4 a4 = *(float4*)&kps[kk][ty * 4];
                float4 b4 = *(float4*)&PV[kk][tx * 4];
                float a[4] = {a4.x, a4.y, a4.z, a4.w};
                float bb[4] = {b4.x, b4.y, b4.z, b4.w};
#pragma unroll
                for (int i = 0; i < 4; i++)
#pragma unroll
                    for (int j = 0; j < 4; j++) acc2[i][j] = fmaf(a[i], bb[j], acc2[i][j]);
            }
            __syncthreads();                             // D: before next staging
        }
        float* __restrict__ ctxp = ws + O_CTX + bh * 16384;
#pragma unroll
        for (int i = 0; i < 4; i++)
#pragma unroll
            for (int j = 0; j < 4; j++)
                atomicAdd(&ctxp[(jq * 64 + ty * 4 + i) * 64 + tx * 4 + j], acc2[i][j]);
    }
    atomicAdd(ws + O_KSUM + bh * 256 + tid, ksum_s[tid]);
}

// ---------------- query-side: dd, rowmax, qp, attG = qp.ctx / (qp.ksum) ----------------
__launch_bounds__(256)
__global__ void k_qout(const float* __restrict__ proj, float* __restrict__ ws) {
    __shared__ float As1[16][64];
    __shared__ float Bs1[16][256];
    __shared__ float qps[64][68];    // qp [n][j-chunk]
    __shared__ float Bs2[64][68];    // ctx chunk [j][d]
    __shared__ float ksum_s[256];
    __shared__ unsigned rmax[64];
    __shared__ float diag_s[64];
    __shared__ float denom_s[64];
    const int bh = blockIdx.x, b = bh / 6, h = bh % 6;
    const int n0 = blockIdx.y * 64;
    const float* __restrict__ Qp = ws + O_Q + (b * 8 + h) * 8192 * 64;
    const float* __restrict__ ctxp = ws + O_CTX + bh * 16384;
    float* __restrict__ attG = ws + O_K;     // [16384][384]
    const int tid = threadIdx.x, tx = tid & 15, ty = tid >> 4;
    if (tid < 64) { rmax[tid] = 0u; diag_s[tid] = 0.f; denom_s[tid] = 0.f; }
    ksum_s[tid] = ws[O_KSUM + bh * 256 + tid];
    float acc1[4][16];
#pragma unroll
    for (int i = 0; i < 4; i++)
#pragma unroll
        for (int j = 0; j < 16; j++) acc1[i][j] = 0.f;
    const int an = tid >> 2, adq = (tid & 3) * 4;

    for (int kt = 0; kt < 4; kt++) {
        const int k0 = kt * 16;
        float4 va = *(const float4*)(Qp + (n0 + an) * 64 + k0 + adq);
        float fp[16];
#pragma unroll
        for (int q = 0; q < 4; q++) {
            float4 p = *(const float4*)(proj + tid * 64 + k0 + q * 4);
            fp[q*4+0] = p.x; fp[q*4+1] = p.y; fp[q*4+2] = p.z; fp[q*4+3] = p.w;
        }
        As1[adq + 0][an] = va.x; As1[adq + 1][an] = va.y;
        As1[adq + 2][an] = va.z; As1[adq + 3][an] = va.w;
#pragma unroll
        for (int l = 0; l < 16; l++) Bs1[l][tid] = fp[l];
        __syncthreads();
        if (tid < 64) {
            float s = diag_s[tid];
#pragma unroll
            for (int kk = 0; kk < 16; kk++) { float v = As1[kk][tid]; s = fmaf(v, v, s); }
            diag_s[tid] = s;
        }
#pragma unroll
        for (int kk = 0; kk < 16; kk++) {
            float4 a4 = *(float4*)&As1[kk][ty * 4];
            float a[4] = {a4.x, a4.y, a4.z, a4.w};
#pragma unroll
            for (int g = 0; g < 4; g++) {
                float4 b4 = *(float4*)&Bs1[kk][g * 64 + tx * 4];
                float bb[4] = {b4.x, b4.y, b4.z, b4.w};
#pragma unroll
                for (int i = 0; i < 4; i++)
#pragma unroll
                    for (int j = 0; j < 4; j++)
                        acc1[i][g * 4 + j] = fmaf(a[i], bb[j], acc1[i][g * 4 + j]);
            }
        }
        __syncthreads();
    }
#pragma unroll
    for (int i = 0; i < 4; i++) {
        float m = acc1[i][0];
#pragma unroll
        for (int c = 1; c < 16; c++) m = fmaxf(m, acc1[i][c]);
        atomicMax(&rmax[ty * 4 + i], encf(m * NORMC));
    }
    __syncthreads();
    float rmx[4], dg[4];
#pragma unroll
    for (int i = 0; i < 4; i++) {
        rmx[i] = decf(rmax[ty * 4 + i]);
        dg[i] = diag_s[ty * 4 + i] * 0.0625f;
    }
    float acc2[4][4];
#pragma unroll
    for (int i = 0; i < 4; i++)
#pragma unroll
        for (int j = 0; j < 4; j++) acc2[i][j] = 0.f;

    for (int jc = 0; jc < 4; jc++) {
#pragma unroll
        for (int i = 0; i < 4; i++) {
            float q0 = RATIO * (expf(fminf(NORMC * acc1[i][jc * 4 + 0] - dg[i] - rmx[i], 0.f)) + KEPS);
            float q1 = RATIO * (expf(fminf(NORMC * acc1[i][jc * 4 + 1] - dg[i] - rmx[i], 0.f)) + KEPS);
            float q2 = RATIO * (expf(fminf(NORMC * acc1[i][jc * 4 + 2] - dg[i] - rmx[i], 0.f)) + KEPS);
            float q3 = RATIO * (expf(fminf(NORMC * acc1[i][jc * 4 + 3] - dg[i] - rmx[i], 0.f)) + KEPS);
            *(float4*)&qps[ty * 4 + i][tx * 4] = make_float4(q0, q1, q2, q3);
            float ds = q0 * ksum_s[jc * 64 + tx * 4 + 0] + q1 * ksum_s[jc * 64 + tx * 4 + 1]
                     + q2 * ksum_s[jc * 64 + tx * 4 + 2] + q3 * ksum_s[jc * 64 + tx * 4 + 3];
            atomicAdd(&denom_s[ty * 4 + i], ds);
        }
        {   // stage ctx chunk
            const int ck = tid >> 2, cdq = (tid & 3) * 16;
#pragma unroll
            for (int wv = 0; wv < 4; wv++) {
                float4 v = *(const float4*)(ctxp + (jc * 64 + ck) * 64 + cdq + 4 * wv);
                *(float4*)&Bs2[ck][cdq + 4 * wv] = v;
            }
        }
        __syncthreads();
#pragma unroll 8
        for (int kk = 0; kk < 64; kk++) {
            float a[4] = {qps[ty * 4 + 0][kk], qps[ty * 4 + 1][kk],
                          qps[ty * 4 + 2][kk], qps[ty * 4 + 3][kk]};
            float4 b4 = *(float4*)&Bs2[kk][tx * 4];
            float bb[4] = {b4.x, b4.y, b4.z, b4.w};
#pragma unroll
            for (int i = 0; i < 4; i++)
#pragma unroll
                for (int j = 0; j < 4; j++) acc2[i][j] = fmaf(a[i], bb[j], acc2[i][j]);
        }
        __syncthreads();
    }
#pragma unroll
    for (int i = 0; i < 4; i++) {
        int n = n0 + ty * 4 + i;
        float inv = 1.0f / fmaxf(denom_s[ty * 4 + i], 1e-30f);
        *(float4*)&attG[(b * 8192 + n) * 384 + h * 64 + tx * 4] =
            make_float4(acc2[i][0] * inv, acc2[i][1] * inv, acc2[i][2] * inv, acc2[i][3] * inv);
    }
}

// ---------------- local windowed attention w/ RoPE, heads 6..7 ----------------
__launch_bounds__(256)
__global__ void k_local(float* __restrict__ ws) {
    __shared__ float Qt[64][64];     // RoPE'd Q, [d][q]
    __shared__ float KtP[64][68];    // RoPE'd K [d][k]; after rowmax barrier reused as pT [k][q]
    __shared__ float Vs[64][68];     // V chunk [k][d]
    __shared__ unsigned rmax_s[64];
    __shared__ float m_s[64], l_s[64], lsum_s[64];
    const int bhp = blockIdx.x, b = bhp >> 1, lh = bhp & 1, h = 6 + lh;
    const int tile = blockIdx.y;                 // 0..127 (64-query tiles)
    const int w = tile >> 2;                     // window index
    const int q0 = tile * 64;
    const float* __restrict__ Qb = ws + O_Q + (b * 8 + h) * 8192 * 64;
    const float* __restrict__ Kb = ws + O_K + (b * 8 + h) * 8192 * 64;
    const float* __restrict__ Vb = ws + O_V + (b * 8 + h) * 8192 * 64;
    const float* __restrict__ cosT = ws + O_COS;
    const float* __restrict__ sinT = ws + O_SIN;
    const int tid = threadIdx.x, tx = tid & 15, ty = tid >> 4;
    const int row = tid >> 2, dq = (tid & 3) * 16;   // staging: 4 threads x 16 dims per row
    const int e = dq & 31;
    const int comp = (dq < 32) ? dq + 32 : dq - 32;
    const float sgn = (dq < 32) ? -1.f : 1.f;

    {   // stage Q tile with RoPE, transposed [d][q]
        const int qpos = q0 + row;
        const float* bp = Qb + qpos * 64;
        const float* cp = cosT + qpos * 32 + e;
        const float* sp = sinT + qpos * 32 + e;
#pragma unroll
        for (int w4 = 0; w4 < 4; w4++) {
            float4 c4 = *(const float4*)(cp + 4 * w4);
            float4 s4 = *(const float4*)(sp + 4 * w4);
            float4 xa = *(const float4*)(bp + dq + 4 * w4);
            float4 xb = *(const float4*)(bp + comp + 4 * w4);
            Qt[dq + 4*w4 + 0][row] = fmaf(sgn * xb.x, s4.x, xa.x * c4.x);
            Qt[dq + 4*w4 + 1][row] = fmaf(sgn * xb.y, s4.y, xa.y * c4.y);
            Qt[dq + 4*w4 + 2][row] = fmaf(sgn * xb.z, s4.z, xa.z * c4.z);
            Qt[dq + 4*w4 + 3][row] = fmaf(sgn * xb.w, s4.w, xa.w * c4.w);
        }
    }
    if (tid < 64) { m_s[tid] = -1e30f; l_s[tid] = 0.f; }
    float O[4][4];
#pragma unroll
    for (int i = 0; i < 4; i++)
#pragma unroll
        for (int j = 0; j < 4; j++) O[i][j] = 0.f;

    for (int c = 0; c < 12; c++) {
        const int kp0 = (w - 1) * 256 + c * 64;
        if (kp0 < 0 || kp0 >= 8192) continue;    // look_around pad (block-uniform)
        {   // stage K chunk (RoPE, transposed) and V chunk
            const int kpos = kp0 + row;
            const float* bp = Kb + kpos * 64;
            const float* cp = cosT + kpos * 32 + e;
            const float* sp = sinT + kpos * 32 + e;
#pragma unroll
            for (int w4 = 0; w4 < 4; w4++) {
                float4 c4 = *(const float4*)(cp + 4 * w4);
                float4 s4 = *(const float4*)(sp + 4 * w4);
                float4 xa = *(const float4*)(bp + dq + 4 * w4);
                float4 xb = *(const float4*)(bp + comp + 4 * w4);
                KtP[dq + 4*w4 + 0][row] = fmaf(sgn * xb.x, s4.x, xa.x * c4.x);
                KtP[dq + 4*w4 + 1][row] = fmaf(sgn * xb.y, s4.y, xa.y * c4.y);
                KtP[dq + 4*w4 + 2][row] = fmaf(sgn * xb.z, s4.z, xa.z * c4.z);
                KtP[dq + 4*w4 + 3][row] = fmaf(sgn * xb.w, s4.w, xa.w * c4.w);
                *(float4*)&Vs[row][dq + 4 * w4] = *(const float4*)(Vb + kpos * 64 + dq + 4 * w4);
            }
        }
        if (tid < 64) { rmax_s[tid] = 0u; lsum_s[tid] = 0.f; }
        __syncthreads();
        float s[4][4];
#pragma unroll
        for (int i = 0; i < 4; i++)
#pragma unroll
            for (int j = 0; j < 4; j++) s[i][j] = 0.f;
#pragma unroll 8
        for (int kk = 0; kk < 64; kk++) {
            float4 a4 = *(float4*)&Qt[kk][ty * 4];
            float4 b4 = *(float4*)&KtP[kk][tx * 4];
            float a[4] = {a4.x, a4.y, a4.z, a4.w};
            float bb[4] = {b4.x, b4.y, b4.z, b4.w};
#pragma unroll
            for (int i = 0; i < 4; i++)
#pragma unroll
                for (int j = 0; j < 4; j++) s[i][j] = fmaf(a[i], bb[j], s[i][j]);
        }
#pragma unroll
        for (int i = 0; i < 4; i++) {
            float rm = -1e30f;
#pragma unroll
            for (int j = 0; j < 4; j++) { s[i][j] *= 0.125f; rm = fmaxf(rm, s[i][j]); }
            atomicMax(&rmax_s[ty * 4 + i], encf(rm));
        }
        __syncthreads();          // rmax done; all KtP reads done -> safe to alias as pT
        float alpha[4];
#pragma unroll
        for (int i = 0; i < 4; i++) {
            const int r = ty * 4 + i;
            float mold = m_s[r];
            float mn = fmaxf(mold, decf(rmax_s[r]));
            alpha[i] = expf(mold - mn);
            float ps = 0.f;
#pragma unroll
            for (int j = 0; j < 4; j++) { s[i][j] = expf(s[i][j] - mn); ps += s[i][j]; }
            atomicAdd(&lsum_s[r], ps);
        }
#pragma unroll
        for (int j = 0; j < 4; j++)
            *(float4*)&KtP[tx * 4 + j][ty * 4] =
                make_float4(s[0][j], s[1][j], s[2][j], s[3][j]);
#pragma unroll
        for (int i = 0; i < 4; i++)
#pragma unroll
            for (int j = 0; j < 4; j++) O[i][j] *= alpha[i];
        __syncthreads();          // pT + lsum complete
        if (tid < 64) {
            float mold = m_s[tid];
            float mn = fmaxf(mold, decf(rmax_s[tid]));
            l_s[tid] = l_s[tid] * expf(mold - mn) + lsum_s[tid];
            m_s[tid] = mn;
        }
#pragma unroll 8
        for (int kk = 0; kk < 64; kk++) {
            float4 a4 = *(float4*)&KtP[kk][ty * 4];
            float4 b4 = *(float4*)&Vs[kk][tx * 4];
            float a[4] = {a4.x, a4.y, a4.z, a4.w};
            float bb[4] = {b4.x, b4.y, b4.z, b4.w};
#pragma unroll
            for (int i = 0; i < 4; i++)
#pragma unroll
                for (int j = 0; j < 4; j++) O[i][j] = fmaf(a[i], bb[j], O[i][j]);
        }
        __syncthreads();          // before next chunk's staging overwrites KtP/Vs
    }
    float* __restrict__ attL = ws + O_ATTL;   // [2][2][8192][64]
#pragma unroll
    for (int i = 0; i < 4; i++) {
        const int q = q0 + ty * 4 + i;
        const float inv = 1.f / fmaxf(l_s[ty * 4 + i], 1e-30f);
        *(float4*)&attL[((b * 2 + lh) * 8192 + q) * 64 + tx * 4] =
            make_float4(O[i][0] * inv, O[i][1] * inv, O[i][2] * inv, O[i][3] * inv);
    }
}

// ---------------- output projection + bias ----------------
__launch_bounds__(256)
__global__ void k_out(const float* __restrict__ Wo,
                      const float* __restrict__ bo,
                      const float* __restrict__ ws,
                      float* __restrict__ out) {
    __shared__ float As[16][128];
    __shared__ float Bs[16][128];
    const float* __restrict__ attG = ws + O_K;      // [16384][384]
    const float* __restrict__ attL = ws + O_ATTL;   // [4][8192][64]
    const int r0 = blockIdx.x * 128, c0 = blockIdx.y * 128;
    const int tid = threadIdx.x, tx = tid & 15, ty = tid >> 4;
    const int am = tid >> 1, ako = (tid & 1) * 8;
    const int bk = tid >> 4, bjo = (tid & 15) * 8;
    float acc[8][8];
#pragma unroll
    for (int i = 0; i < 8; i++)
#pragma unroll
        for (int j = 0; j < 8; j++) acc[i][j] = 0.f;

    for (int k0 = 0; k0 < 512; k0 += 16) {
        const int row = r0 + am;
        float4 a0, a1;
        if (k0 < 384) {
            a0 = *(const float4*)(attG + row * 384 + k0 + ako);
            a1 = *(const float4*)(attG + row * 384 + k0 + ako + 4);
        } else {
            const int bb = row >> 13, nn = row & 8191;
            const int kk0 = k0 + ako - 384;
            const int lhh = kk0 >> 6, dd = kk0 & 63;
            const float* src = attL + ((bb * 2 + lhh) * 8192 + nn) * 64 + dd;
            a0 = *(const float4*)(src);
            a1 = *(const float4*)(src + 4);
        }
        float4 b0 = *(const float4*)(Wo + (k0 + bk) * 512 + c0 + bjo);
        float4 b1 = *(const float4*)(Wo + (k0 + bk) * 512 + c0 + bjo + 4);
        As[ako + 0][am] = a0.x; As[ako + 1][am] = a0.y;
        As[ako + 2][am] = a0.z; As[ako + 3][am] = a0.w;
        As[ako + 4][am] = a1.x; As[ako + 5][am] = a1.y;
        As[ako + 6][am] = a1.z; As[ako + 7][am] = a1.w;
        *(float4*)&Bs[bk][bjo]     = b0;
        *(float4*)&Bs[bk][bjo + 4] = b1;
        __syncthreads();
#pragma unroll
        for (int kk = 0; kk < 16; kk++) {
            float4 a04 = *(float4*)&As[kk][ty * 8];
            float4 a14 = *(float4*)&As[kk][ty * 8 + 4];
            float4 b04 = *(float4*)&Bs[kk][tx * 4];
            float4 b14 = *(float4*)&Bs[kk][64 + tx * 4];
            float a[8] = {a04.x, a04.y, a04.z, a04.w, a14.x, a14.y, a14.z, a14.w};
            float b[8] = {b04.x, b04.y, b04.z, b04.w, b14.x, b14.y, b14.z, b14.w};
#pragma unroll
            for (int i = 0; i < 8; i++)
#pragma unroll
                for (int j = 0; j < 8; j++) acc[i][j] = fmaf(a[i], b[j], acc[i][j]);
        }
        __syncthreads();
    }
    const int col0 = c0 + tx * 4, col1 = c0 + 64 + tx * 4;
    float4 bo0 = *(const float4*)(bo + col0);
    float4 bo1 = *(const float4*)(bo + col1);
#pragma unroll
    for (int i = 0; i < 8; i++) {
        int r = r0 + ty * 8 + i;
        *(float4*)&out[r * 512 + col0] =
            make_float4(acc[i][0] + bo0.x, acc[i][1] + bo0.y, acc[i][2] + bo0.z, acc[i][3] + bo0.w);
        *(float4*)&out[r * 512 + col1] =
            make_float4(acc[i][4] + bo1.x, acc[i][5] + bo1.y, acc[i][6] + bo1.z, acc[i][7] + bo1.w);
    }
}

extern "C" void kernel_launch(void* const* d_in, const int* in_sizes, int n_in,
                              void* d_out, int out_size, void* d_ws, size_t ws_size,
                              hipStream_t stream) {
    const float* x    = (const float*)d_in[0];
    const float* Wq   = (const float*)d_in[1];
    const float* Wk   = (const float*)d_in[2];
    const float* Wv   = (const float*)d_in[3];
    const float* Wo   = (const float*)d_in[4];
    const float* bo   = (const float*)d_in[5];
    const float* proj = (const float*)d_in[6];
    float* ws = (float*)d_ws;
    float* out = (float*)d_out;

    hipMemsetAsync(d_ws, 0, (size_t)O_ZEND * 4, stream);                 // kmax/ksum/ctx
    hipLaunchKernelGGL(k_rope,   dim3(1024), dim3(256), 0, stream, ws);
    hipLaunchKernelGGL(k_half_w, dim3(8, 8, 3), dim3(256), 0, stream, Wq, Wk, Wv, ws);
    hipLaunchKernelGGL(k_qkv,    dim3(128, 4, 3), dim3(256), 0, stream, x, ws);
    hipLaunchKernelGGL(k_kmax,   dim3(12, 128), dim3(256), 0, stream, proj, ws);
    hipLaunchKernelGGL(k_kctx,   dim3(12, 64), dim3(256), 0, stream, proj, ws);
    hipLaunchKernelGGL(k_local,  dim3(4, 128), dim3(256), 0, stream, ws);   // before k_qout!
    hipLaunchKernelGGL(k_qout,   dim3(12, 128), dim3(256), 0, stream, proj, ws);
    hipLaunchKernelGGL(k_out,    dim3(128, 4), dim3(256), 0, stream, Wo, bo, ws, out);
}

// Round 7
// 640.825 us; speedup vs baseline: 2.8002x; 1.2735x over previous
//
#include <hip/hip_runtime.h>

// ---------------- constants ----------------
#define NTOK 8192
#define NORMC 0.35355339059327373f   // 64^-0.25
#define RATIO 0.0625f                // 256^-0.5
#define KEPS  1e-4f

// ws offsets in 4-byte elements  (total 27987008 ele = 106.8 MB)
#define O_KMAX 0                      // 12 x u32 (encoded max)
#define O_KSUM 64                     // 12*256 f32
#define O_CTX  3136                   // 12*256*64 f32
#define O_ZEND 199744                 // zeroed region end
#define O_COS  199744                 // 8192*32
#define O_SIN  461888                 // 8192*32
#define O_Q    724032                 // 2*8*8192*64
#define O_K    9112640                // K; later reused as attG [16384][384]
#define O_V    17501248
#define O_ATTL 25889856               // 2*2*8192*64 (local heads out)
// O_WH: fp16 W^T [3][512][512] lives in the ATTL region (dead until k_local,
// consumed only by k_qkv which runs first) -> zero footprint growth
#define O_WH   25889856
// end: 27987008

typedef _Float16 half8 __attribute__((ext_vector_type(8)));
typedef _Float16 half4h __attribute__((ext_vector_type(4)));
typedef float floatx4 __attribute__((ext_vector_type(4)));

__device__ __forceinline__ unsigned encf(float f) {
    unsigned u = __float_as_uint(f);
    return (u & 0x80000000u) ? ~u : (u | 0x80000000u);
}
__device__ __forceinline__ float decf(unsigned u) {
    return (u & 0x80000000u) ? __uint_as_float(u & 0x7fffffffu) : __uint_as_float(~u);
}

// ---------------- RoPE tables (double precision angles) ----------------
__global__ void k_rope(float* __restrict__ ws) {
    int idx = blockIdx.x * 256 + threadIdx.x;      // 8192*32
    int t = idx >> 5, i = idx & 31;
    double invf = pow(10000.0, -(double)(2 * i) / 64.0);
    double ang = (double)t * invf;
    ws[O_COS + idx] = (float)cos(ang);
    ws[O_SIN + idx] = (float)sin(ang);
}

// ---------------- W -> fp16, transposed to [n][k] ----------------
__launch_bounds__(256)
__global__ void k_half_w(const float* __restrict__ Wq,
                         const float* __restrict__ Wk,
                         const float* __restrict__ Wv,
                         float* __restrict__ ws) {
    __shared__ float T[64][65];
    const int z = blockIdx.z;
    const float* __restrict__ W = (z == 0) ? Wq : ((z == 1) ? Wk : Wv);
    _Float16* __restrict__ Wt = (_Float16*)(ws + O_WH) + (size_t)z * 262144;
    const int k0 = blockIdx.x * 64, n0 = blockIdx.y * 64;
    const int lx = threadIdx.x & 63, ly = threadIdx.x >> 6;   // ly in 0..3
#pragma unroll
    for (int i = 0; i < 16; i++) {
        const int kk = ly * 16 + i;
        T[lx][kk] = W[(k0 + kk) * 512 + n0 + lx];    // T[n-n0][k-k0]
    }
    __syncthreads();
#pragma unroll
    for (int i = 0; i < 16; i++) {
        const int nn = ly * 16 + i;
        Wt[(n0 + nn) * 512 + k0 + lx] = (_Float16)T[nn][lx];
    }
}

// ---------------- QKV projection via fp16 MFMA ----------------
__launch_bounds__(256)
__global__ void k_qkv(const float* __restrict__ x, float* __restrict__ ws) {
    __shared__ _Float16 Ah[128 * 72];
    __shared__ _Float16 Bh[128 * 72];
    const int z = blockIdx.z;
    const _Float16* __restrict__ Wt = (const _Float16*)(ws + O_WH) + (size_t)z * 262144;
    float* __restrict__ out = ws + ((z == 0) ? O_Q : ((z == 1) ? O_K : O_V));
    const int r0 = blockIdx.x * 128, c0 = blockIdx.y * 128;
    const int tid = threadIdx.x;
    const int wv = tid >> 6, lane = tid & 63, lm = lane & 15, lq = lane >> 4;
    const int srow = tid >> 1, skoff = (tid & 1) * 32;
    floatx4 acc[2][8];
#pragma unroll
    for (int m = 0; m < 2; m++)
#pragma unroll
        for (int n = 0; n < 8; n++) acc[m][n] = (floatx4){0.f, 0.f, 0.f, 0.f};

    for (int c = 0; c < 8; c++) {
        const int k0 = c * 64;
        {   // stage A: x fp32 -> fp16 (row-major, k contiguous)
            const float* ap = x + (size_t)(r0 + srow) * 512 + k0 + skoff;
#pragma unroll
            for (int q = 0; q < 4; q++) {
                float4 v0 = *(const float4*)(ap + 8 * q);
                float4 v1 = *(const float4*)(ap + 8 * q + 4);
                half8 h = {(_Float16)v0.x, (_Float16)v0.y, (_Float16)v0.z, (_Float16)v0.w,
                           (_Float16)v1.x, (_Float16)v1.y, (_Float16)v1.z, (_Float16)v1.w};
                *(half8*)&Ah[srow * 72 + skoff + 8 * q] = h;
            }
        }
        {   // stage B: fp16 W^T direct copy
            const _Float16* bp = Wt + (size_t)(c0 + srow) * 512 + k0 + skoff;
#pragma unroll
            for (int q = 0; q < 4; q++)
                *(uint4*)&Bh[srow * 72 + skoff + 8 * q] = *(const uint4*)(bp + 8 * q);
        }
        __syncthreads();
#pragma unroll
        for (int ks = 0; ks < 2; ks++) {
            half8 af[2], bf[8];
            af[0] = *(half8*)&Ah[(wv * 32 + lm) * 72 + ks * 32 + lq * 8];
            af[1] = *(half8*)&Ah[(wv * 32 + 16 + lm) * 72 + ks * 32 + lq * 8];
#pragma unroll
            for (int n = 0; n < 8; n++)
                bf[n] = *(half8*)&Bh[(n * 16 + lm) * 72 + ks * 32 + lq * 8];
#pragma unroll
            for (int m = 0; m < 2; m++)
#pragma unroll
                for (int n = 0; n < 8; n++)
                    acc[m][n] = __builtin_amdgcn_mfma_f32_16x16x32_f16(af[m], bf[n], acc[m][n], 0, 0, 0);
        }
        __syncthreads();
    }
    const int bi = r0 >> 13;
#pragma unroll
    for (int n = 0; n < 8; n++) {
        const int col = c0 + n * 16 + lm;
        const int h = col >> 6, d = col & 63;
#pragma unroll
        for (int m = 0; m < 2; m++) {
            const int rbase = r0 + wv * 32 + m * 16 + lq * 4;
#pragma unroll
            for (int j = 0; j < 4; j++) {
                const int ng = (rbase + j) & 8191;
                out[((size_t)(bi * 8 + h) * 8192 + ng) * 64 + d] = acc[m][n][j];
            }
        }
    }
}

// ---------------- key-side global max of dd = norm*(K.projT) ----------------
__launch_bounds__(256)
__global__ void k_kmax(const float* __restrict__ proj, float* __restrict__ ws) {
    __shared__ float As[16][64];     // [d][n]
    __shared__ float Bs[16][256];    // [d][j]
    __shared__ unsigned bmax;
    const int bh = blockIdx.x, b = bh / 6, h = bh % 6;
    const float* __restrict__ Kp = ws + O_K + (b * 8 + h) * 8192 * 64;
    const int n0 = blockIdx.y * 64;
    const int tid = threadIdx.x, tx = tid & 15, ty = tid >> 4;
    if (tid == 0) bmax = 0u;
    const int an = tid >> 2, adq = (tid & 3) * 4;
    float acc[4][16];
#pragma unroll
    for (int i = 0; i < 4; i++)
#pragma unroll
        for (int j = 0; j < 16; j++) acc[i][j] = 0.f;

    for (int k0 = 0; k0 < 64; k0 += 16) {
        float4 va = *(const float4*)(Kp + (n0 + an) * 64 + k0 + adq);
        float fp[16];
#pragma unroll
        for (int q = 0; q < 4; q++) {
            float4 p = *(const float4*)(proj + tid * 64 + k0 + q * 4);
            fp[q*4+0] = p.x; fp[q*4+1] = p.y; fp[q*4+2] = p.z; fp[q*4+3] = p.w;
        }
        As[adq + 0][an] = va.x; As[adq + 1][an] = va.y;
        As[adq + 2][an] = va.z; As[adq + 3][an] = va.w;
#pragma unroll
        for (int l = 0; l < 16; l++) Bs[l][tid] = fp[l];
        __syncthreads();
#pragma unroll
        for (int kk = 0; kk < 16; kk++) {
            float4 a4 = *(float4*)&As[kk][ty * 4];
            float a[4] = {a4.x, a4.y, a4.z, a4.w};
#pragma unroll
            for (int g = 0; g < 4; g++) {
                float4 b4 = *(float4*)&Bs[kk][g * 64 + tx * 4];
                float bb[4] = {b4.x, b4.y, b4.z, b4.w};
#pragma unroll
                for (int i = 0; i < 4; i++)
#pragma unroll
                    for (int j = 0; j < 4; j++)
                        acc[i][g * 4 + j] = fmaf(a[i], bb[j], acc[i][g * 4 + j]);
            }
        }
        __syncthreads();
    }
    float m = acc[0][0];
#pragma unroll
    for (int i = 0; i < 4; i++)
#pragma unroll
        for (int j = 0; j < 16; j++) m = fmaxf(m, acc[i][j]);
    atomicMax(&bmax, encf(m * NORMC));
    __syncthreads();
    if (tid == 0) atomicMax((unsigned*)ws + O_KMAX + bh, bmax);
}

// ---------------- key-side: kp, k_sum, ctx = kp^T @ V  (fp16 MFMA) ----------------
// Grid (12 bh, 32 n-chunks of 256, 2 j-halves of 128). 4 waves; wave w owns
// j-range w*32 within the half. Per 64-row n-sub: dd=K.projT (MFMA), exp in
// C-layout regs, kp->LDS [j][n] fp16, ctx += kp^T.V (MFMA, V staged [d][n]).
// ctx persists in 32 regs/lane, flushed once. LDS ~53 KB -> 3 blocks/CU.
__launch_bounds__(256)
__global__ void k_kctx(const float* __restrict__ proj, float* __restrict__ ws) {
    __shared__ _Float16 Kh[64 * 68];     // K sub [n][d]
    __shared__ _Float16 Vt[64 * 68];     // V sub transposed [d][n]
    __shared__ _Float16 Ph[128 * 68];    // proj half [j][d]
    __shared__ _Float16 kpt[128 * 68];   // kp transposed [j][n]
    __shared__ float diag4[64][4];       // per-row |K|^2 partials (race-free)
    __shared__ float ksum_s[128];
    const int bh = blockIdx.x, b = bh / 6, h = bh % 6;
    const int n0 = blockIdx.y * 256;
    const int jh = blockIdx.z;
    const float* __restrict__ Kp = ws + O_K + (size_t)(b * 8 + h) * 8192 * 64;
    const float* __restrict__ Vp = ws + O_V + (size_t)(b * 8 + h) * 8192 * 64;
    const float kmax = decf(((const unsigned*)ws)[O_KMAX + bh]);
    const int tid = threadIdx.x;
    const int wv = tid >> 6, lane = tid & 63, lm = lane & 15, lq = lane >> 4;
    if (tid < 128) ksum_s[tid] = 0.f;

    {   // stage Ph once: proj rows jh*128.., [jrel][d] stride 68
        const int r = tid >> 1, doff = (tid & 1) * 32;
        const float* pp = proj + (jh * 128 + r) * 64 + doff;
#pragma unroll
        for (int q = 0; q < 4; q++) {
            float4 v0 = *(const float4*)(pp + 8 * q);
            float4 v1 = *(const float4*)(pp + 8 * q + 4);
            half8 hv = {(_Float16)v0.x, (_Float16)v0.y, (_Float16)v0.z, (_Float16)v0.w,
                        (_Float16)v1.x, (_Float16)v1.y, (_Float16)v1.z, (_Float16)v1.w};
            *(half8*)&Ph[r * 68 + doff + 8 * q] = hv;
        }
    }
    floatx4 acc[2][4];   // ctx tiles [jt][dt]
#pragma unroll
    for (int jt = 0; jt < 2; jt++)
#pragma unroll
        for (int dt = 0; dt < 4; dt++) acc[jt][dt] = (floatx4){0.f, 0.f, 0.f, 0.f};

    for (int nc = 0; nc < 4; nc++) {
        const int ns = n0 + nc * 64;
        {   // stage Kh [n][d] + diag partials
            const int r = tid >> 2, dq = (tid & 3) * 16;
            const float* kpp = Kp + (size_t)(ns + r) * 64 + dq;
            float part = 0.f;
            _Float16 t[16];
#pragma unroll
            for (int q = 0; q < 4; q++) {
                float4 v = *(const float4*)(kpp + 4 * q);
                part = fmaf(v.x, v.x, fmaf(v.y, v.y, fmaf(v.z, v.z, fmaf(v.w, v.w, part))));
                t[4*q+0] = (_Float16)v.x; t[4*q+1] = (_Float16)v.y;
                t[4*q+2] = (_Float16)v.z; t[4*q+3] = (_Float16)v.w;
            }
            *(half8*)&Kh[r * 68 + dq]     = *(half8*)&t[0];
            *(half8*)&Kh[r * 68 + dq + 8] = *(half8*)&t[8];
            diag4[r][tid & 3] = part;
        }
        {   // stage Vt transposed [d][n]: thread d = tid&63, n-block of 16
            const int d = tid & 63, nb = (tid >> 6) * 16;
            _Float16 t[16];
#pragma unroll
            for (int i = 0; i < 16; i++)
                t[i] = (_Float16)Vp[(size_t)(ns + nb + i) * 64 + d];
            *(half8*)&Vt[d * 68 + nb]     = *(half8*)&t[0];
            *(half8*)&Vt[d * 68 + nb + 8] = *(half8*)&t[8];
        }
        __syncthreads();                              // A: Kh/Vt/diag4 ready (kpt free)
        // dd[n][j]: M=64 n, N=32 j (this wave), K=64
        floatx4 s4[4][2];
#pragma unroll
        for (int nt = 0; nt < 4; nt++)
#pragma unroll
            for (int jt = 0; jt < 2; jt++) s4[nt][jt] = (floatx4){0.f, 0.f, 0.f, 0.f};
#pragma unroll
        for (int ks = 0; ks < 2; ks++) {
            half8 af[4], bf[2];
#pragma unroll
            for (int nt = 0; nt < 4; nt++)
                af[nt] = *(half8*)&Kh[(nt * 16 + lm) * 68 + ks * 32 + lq * 8];
#pragma unroll
            for (int jt = 0; jt < 2; jt++)
                bf[jt] = *(half8*)&Ph[(wv * 32 + jt * 16 + lm) * 68 + ks * 32 + lq * 8];
#pragma unroll
            for (int nt = 0; nt < 4; nt++)
#pragma unroll
                for (int jt = 0; jt < 2; jt++)
                    s4[nt][jt] = __builtin_amdgcn_mfma_f32_16x16x32_f16(af[nt], bf[jt], s4[nt][jt], 0, 0, 0);
        }
        // exp in C-layout (col=j=lm, row=n=lq*4+reg), kp -> kpt [j][n] fp16
        float jsum[2] = {0.f, 0.f};
#pragma unroll
        for (int nt = 0; nt < 4; nt++) {
            float dg[4];
#pragma unroll
            for (int r = 0; r < 4; r++) {
                float4 d4 = *(float4*)diag4[nt * 16 + lq * 4 + r];   // broadcast read
                dg[r] = (d4.x + d4.y + d4.z + d4.w) * 0.0625f;
            }
#pragma unroll
            for (int jt = 0; jt < 2; jt++) {
                half4h kv;
#pragma unroll
                for (int r = 0; r < 4; r++) {
                    float v = RATIO * (expf(fminf(NORMC * s4[nt][jt][r] - dg[r] - kmax, 0.f)) + KEPS);
                    jsum[jt] += v;
                    kv[r] = (_Float16)v;
                }
                *(half4h*)&kpt[(wv * 32 + jt * 16 + lm) * 68 + nt * 16 + lq * 4] = kv;
            }
        }
#pragma unroll
        for (int jt = 0; jt < 2; jt++)
            atomicAdd(&ksum_s[wv * 32 + jt * 16 + lm], jsum[jt]);
        __syncthreads();                              // B: kpt ready
        // ctx[j][d] += kp^T @ V: M=32 j (this wave), N=64 d, K=64 n
#pragma unroll
        for (int ks = 0; ks < 2; ks++) {
            half8 af[2], bf[4];
#pragma unroll
            for (int jt = 0; jt < 2; jt++)
                af[jt] = *(half8*)&kpt[(wv * 32 + jt * 16 + lm) * 68 + ks * 32 + lq * 8];
#pragma unroll
            for (int dt = 0; dt < 4; dt++)
                bf[dt] = *(half8*)&Vt[(dt * 16 + lm) * 68 + ks * 32 + lq * 8];
#pragma unroll
            for (int jt = 0; jt < 2; jt++)
#pragma unroll
                for (int dt = 0; dt < 4; dt++)
                    acc[jt][dt] = __builtin_amdgcn_mfma_f32_16x16x32_f16(af[jt], bf[dt], acc[jt][dt], 0, 0, 0);
        }
        __syncthreads();                              // D: before next staging
    }
    // flush: C-layout col=d=lm, row=j=lq*4+reg
    float* __restrict__ ctxp = ws + O_CTX + bh * 16384;
#pragma unroll
    for (int jt = 0; jt < 2; jt++) {
#pragma unroll
        for (int dt = 0; dt < 4; dt++) {
            const int d = dt * 16 + lm;
#pragma unroll
            for (int r = 0; r < 4; r++) {
                const int j = jh * 128 + wv * 32 + jt * 16 + lq * 4 + r;
                atomicAdd(&ctxp[j * 64 + d], acc[jt][dt][r]);
            }
        }
    }
    if (tid < 128) atomicAdd(ws + O_KSUM + bh * 256 + jh * 128 + tid, ksum_s[tid]);
}

// ---------------- query-side: dd, rowmax, qp, attG = qp.ctx / (qp.ksum) ----------------
__launch_bounds__(256)
__global__ void k_qout(const float* __restrict__ proj, float* __restrict__ ws) {
    __shared__ float As1[16][64];
    __shared__ float Bs1[16][256];
    __shared__ float qps[64][68];    // qp [n][j-chunk]
    __shared__ float Bs2[64][68];    // ctx chunk [j][d]
    __shared__ float ksum_s[256];
    __shared__ unsigned rmax[64];
    __shared__ float diag_s[64];
    __shared__ float denom_s[64];
    const int bh = blockIdx.x, b = bh / 6, h = bh % 6;
    const int n0 = blockIdx.y * 64;
    const float* __restrict__ Qp = ws + O_Q + (b * 8 + h) * 8192 * 64;
    const float* __restrict__ ctxp = ws + O_CTX + bh * 16384;
    float* __restrict__ attG = ws + O_K;     // [16384][384]
    const int tid = threadIdx.x, tx = tid & 15, ty = tid >> 4;
    if (tid < 64) { rmax[tid] = 0u; diag_s[tid] = 0.f; denom_s[tid] = 0.f; }
    ksum_s[tid] = ws[O_KSUM + bh * 256 + tid];
    float acc1[4][16];
#pragma unroll
    for (int i = 0; i < 4; i++)
#pragma unroll
        for (int j = 0; j < 16; j++) acc1[i][j] = 0.f;
    const int an = tid >> 2, adq = (tid & 3) * 4;

    for (int kt = 0; kt < 4; kt++) {
        const int k0 = kt * 16;
        float4 va = *(const float4*)(Qp + (n0 + an) * 64 + k0 + adq);
        float fp[16];
#pragma unroll
        for (int q = 0; q < 4; q++) {
            float4 p = *(const float4*)(proj + tid * 64 + k0 + q * 4);
            fp[q*4+0] = p.x; fp[q*4+1] = p.y; fp[q*4+2] = p.z; fp[q*4+3] = p.w;
        }
        As1[adq + 0][an] = va.x; As1[adq + 1][an] = va.y;
        As1[adq + 2][an] = va.z; As1[adq + 3][an] = va.w;
#pragma unroll
        for (int l = 0; l < 16; l++) Bs1[l][tid] = fp[l];
        __syncthreads();
        if (tid < 64) {
            float s = diag_s[tid];
#pragma unroll
            for (int kk = 0; kk < 16; kk++) { float v = As1[kk][tid]; s = fmaf(v, v, s); }
            diag_s[tid] = s;
        }
#pragma unroll
        for (int kk = 0; kk < 16; kk++) {
            float4 a4 = *(float4*)&As1[kk][ty * 4];
            float a[4] = {a4.x, a4.y, a4.z, a4.w};
#pragma unroll
            for (int g = 0; g < 4; g++) {
                float4 b4 = *(float4*)&Bs1[kk][g * 64 + tx * 4];
                float bb[4] = {b4.x, b4.y, b4.z, b4.w};
#pragma unroll
                for (int i = 0; i < 4; i++)
#pragma unroll
                    for (int j = 0; j < 4; j++)
                        acc1[i][g * 4 + j] = fmaf(a[i], bb[j], acc1[i][g * 4 + j]);
            }
        }
        __syncthreads();
    }
#pragma unroll
    for (int i = 0; i < 4; i++) {
        float m = acc1[i][0];
#pragma unroll
        for (int c = 1; c < 16; c++) m = fmaxf(m, acc1[i][c]);
        atomicMax(&rmax[ty * 4 + i], encf(m * NORMC));
    }
    __syncthreads();
    float rmx[4], dg[4];
#pragma unroll
    for (int i = 0; i < 4; i++) {
        rmx[i] = decf(rmax[ty * 4 + i]);
        dg[i] = diag_s[ty * 4 + i] * 0.0625f;
    }
    float acc2[4][4];
#pragma unroll
    for (int i = 0; i < 4; i++)
#pragma unroll
        for (int j = 0; j < 4; j++) acc2[i][j] = 0.f;

    for (int jc = 0; jc < 4; jc++) {
#pragma unroll
        for (int i = 0; i < 4; i++) {
            float q0 = RATIO * (expf(fminf(NORMC * acc1[i][jc * 4 + 0] - dg[i] - rmx[i], 0.f)) + KEPS);
            float q1 = RATIO * (expf(fminf(NORMC * acc1[i][jc * 4 + 1] - dg[i] - rmx[i], 0.f)) + KEPS);
            float q2 = RATIO * (expf(fminf(NORMC * acc1[i][jc * 4 + 2] - dg[i] - rmx[i], 0.f)) + KEPS);
            float q3 = RATIO * (expf(fminf(NORMC * acc1[i][jc * 4 + 3] - dg[i] - rmx[i], 0.f)) + KEPS);
            *(float4*)&qps[ty * 4 + i][tx * 4] = make_float4(q0, q1, q2, q3);
            float ds = q0 * ksum_s[jc * 64 + tx * 4 + 0] + q1 * ksum_s[jc * 64 + tx * 4 + 1]
                     + q2 * ksum_s[jc * 64 + tx * 4 + 2] + q3 * ksum_s[jc * 64 + tx * 4 + 3];
            atomicAdd(&denom_s[ty * 4 + i], ds);
        }
        {   // stage ctx chunk
            const int ck = tid >> 2, cdq = (tid & 3) * 16;
#pragma unroll
            for (int wv = 0; wv < 4; wv++) {
                float4 v = *(const float4*)(ctxp + (jc * 64 + ck) * 64 + cdq + 4 * wv);
                *(float4*)&Bs2[ck][cdq + 4 * wv] = v;
            }
        }
        __syncthreads();
#pragma unroll 8
        for (int kk = 0; kk < 64; kk++) {
            float a[4] = {qps[ty * 4 + 0][kk], qps[ty * 4 + 1][kk],
                          qps[ty * 4 + 2][kk], qps[ty * 4 + 3][kk]};
            float4 b4 = *(float4*)&Bs2[kk][tx * 4];
            float bb[4] = {b4.x, b4.y, b4.z, b4.w};
#pragma unroll
            for (int i = 0; i < 4; i++)
#pragma unroll
                for (int j = 0; j < 4; j++) acc2[i][j] = fmaf(a[i], bb[j], acc2[i][j]);
        }
        __syncthreads();
    }
#pragma unroll
    for (int i = 0; i < 4; i++) {
        int n = n0 + ty * 4 + i;
        float inv = 1.0f / fmaxf(denom_s[ty * 4 + i], 1e-30f);
        *(float4*)&attG[(b * 8192 + n) * 384 + h * 64 + tx * 4] =
            make_float4(acc2[i][0] * inv, acc2[i][1] * inv, acc2[i][2] * inv, acc2[i][3] * inv);
    }
}

// ---------------- local windowed attention w/ RoPE, heads 6..7 ----------------
__launch_bounds__(256)
__global__ void k_local(float* __restrict__ ws) {
    __shared__ float Qt[64][64];     // RoPE'd Q, [d][q]
    __shared__ float KtP[64][68];    // RoPE'd K [d][k]; after rowmax barrier reused as pT [k][q]
    __shared__ float Vs[64][68];     // V chunk [k][d]
    __shared__ unsigned rmax_s[64];
    __shared__ float m_s[64], l_s[64], lsum_s[64];
    const int bhp = blockIdx.x, b = bhp >> 1, lh = bhp & 1, h = 6 + lh;
    const int tile = blockIdx.y;                 // 0..127 (64-query tiles)
    const int w = tile >> 2;                     // window index
    const int q0 = tile * 64;
    const float* __restrict__ Qb = ws + O_Q + (b * 8 + h) * 8192 * 64;
    const float* __restrict__ Kb = ws + O_K + (b * 8 + h) * 8192 * 64;
    const float* __restrict__ Vb = ws + O_V + (b * 8 + h) * 8192 * 64;
    const float* __restrict__ cosT = ws + O_COS;
    const float* __restrict__ sinT = ws + O_SIN;
    const int tid = threadIdx.x, tx = tid & 15, ty = tid >> 4;
    const int row = tid >> 2, dq = (tid & 3) * 16;   // staging: 4 threads x 16 dims per row
    const int e = dq & 31;
    const int comp = (dq < 32) ? dq + 32 : dq - 32;
    const float sgn = (dq < 32) ? -1.f : 1.f;

    {   // stage Q tile with RoPE, transposed [d][q]
        const int qpos = q0 + row;
        const float* bp = Qb + qpos * 64;
        const float* cp = cosT + qpos * 32 + e;
        const float* sp = sinT + qpos * 32 + e;
#pragma unroll
        for (int w4 = 0; w4 < 4; w4++) {
            float4 c4 = *(const float4*)(cp + 4 * w4);
            float4 s4 = *(const float4*)(sp + 4 * w4);
            float4 xa = *(const float4*)(bp + dq + 4 * w4);
            float4 xb = *(const float4*)(bp + comp + 4 * w4);
            Qt[dq + 4*w4 + 0][row] = fmaf(sgn * xb.x, s4.x, xa.x * c4.x);
            Qt[dq + 4*w4 + 1][row] = fmaf(sgn * xb.y, s4.y, xa.y * c4.y);
            Qt[dq + 4*w4 + 2][row] = fmaf(sgn * xb.z, s4.z, xa.z * c4.z);
            Qt[dq + 4*w4 + 3][row] = fmaf(sgn * xb.w, s4.w, xa.w * c4.w);
        }
    }
    if (tid < 64) { m_s[tid] = -1e30f; l_s[tid] = 0.f; }
    float O[4][4];
#pragma unroll
    for (int i = 0; i < 4; i++)
#pragma unroll
        for (int j = 0; j < 4; j++) O[i][j] = 0.f;

    for (int c = 0; c < 12; c++) {
        const int kp0 = (w - 1) * 256 + c * 64;
        if (kp0 < 0 || kp0 >= 8192) continue;    // look_around pad (block-uniform)
        {   // stage K chunk (RoPE, transposed) and V chunk
            const int kpos = kp0 + row;
            const float* bp = Kb + kpos * 64;
            const float* cp = cosT + kpos * 32 + e;
            const float* sp = sinT + kpos * 32 + e;
#pragma unroll
            for (int w4 = 0; w4 < 4; w4++) {
                float4 c4 = *(const float4*)(cp + 4 * w4);
                float4 s4 = *(const float4*)(sp + 4 * w4);
                float4 xa = *(const float4*)(bp + dq + 4 * w4);
                float4 xb = *(const float4*)(bp + comp + 4 * w4);
                KtP[dq + 4*w4 + 0][row] = fmaf(sgn * xb.x, s4.x, xa.x * c4.x);
                KtP[dq + 4*w4 + 1][row] = fmaf(sgn * xb.y, s4.y, xa.y * c4.y);
                KtP[dq + 4*w4 + 2][row] = fmaf(sgn * xb.z, s4.z, xa.z * c4.z);
                KtP[dq + 4*w4 + 3][row] = fmaf(sgn * xb.w, s4.w, xa.w * c4.w);
                *(float4*)&Vs[row][dq + 4 * w4] = *(const float4*)(Vb + kpos * 64 + dq + 4 * w4);
            }
        }
        if (tid < 64) { rmax_s[tid] = 0u; lsum_s[tid] = 0.f; }
        __syncthreads();
        float s[4][4];
#pragma unroll
        for (int i = 0; i < 4; i++)
#pragma unroll
            for (int j = 0; j < 4; j++) s[i][j] = 0.f;
#pragma unroll 8
        for (int kk = 0; kk < 64; kk++) {
            float4 a4 = *(float4*)&Qt[kk][ty * 4];
            float4 b4 = *(float4*)&KtP[kk][tx * 4];
            float a[4] = {a4.x, a4.y, a4.z, a4.w};
            float bb[4] = {b4.x, b4.y, b4.z, b4.w};
#pragma unroll
            for (int i = 0; i < 4; i++)
#pragma unroll
                for (int j = 0; j < 4; j++) s[i][j] = fmaf(a[i], bb[j], s[i][j]);
        }
#pragma unroll
        for (int i = 0; i < 4; i++) {
            float rm = -1e30f;
#pragma unroll
            for (int j = 0; j < 4; j++) { s[i][j] *= 0.125f; rm = fmaxf(rm, s[i][j]); }
            atomicMax(&rmax_s[ty * 4 + i], encf(rm));
        }
        __syncthreads();          // rmax done; all KtP reads done -> safe to alias as pT
        float alpha[4];
#pragma unroll
        for (int i = 0; i < 4; i++) {
            const int r = ty * 4 + i;
            float mold = m_s[r];
            float mn = fmaxf(mold, decf(rmax_s[r]));
            alpha[i] = expf(mold - mn);
            float ps = 0.f;
#pragma unroll
            for (int j = 0; j < 4; j++) { s[i][j] = expf(s[i][j] - mn); ps += s[i][j]; }
            atomicAdd(&lsum_s[r], ps);
        }
#pragma unroll
        for (int j = 0; j < 4; j++)
            *(float4*)&KtP[tx * 4 + j][ty * 4] =
                make_float4(s[0][j], s[1][j], s[2][j], s[3][j]);
#pragma unroll
        for (int i = 0; i < 4; i++)
#pragma unroll
            for (int j = 0; j < 4; j++) O[i][j] *= alpha[i];
        __syncthreads();          // pT + lsum complete
        if (tid < 64) {
            float mold = m_s[tid];
            float mn = fmaxf(mold, decf(rmax_s[tid]));
            l_s[tid] = l_s[tid] * expf(mold - mn) + lsum_s[tid];
            m_s[tid] = mn;
        }
#pragma unroll 8
        for (int kk = 0; kk < 64; kk++) {
            float4 a4 = *(float4*)&KtP[kk][ty * 4];
            float4 b4 = *(float4*)&Vs[kk][tx * 4];
            float a[4] = {a4.x, a4.y, a4.z, a4.w};
            float bb[4] = {b4.x, b4.y, b4.z, b4.w};
#pragma unroll
            for (int i = 0; i < 4; i++)
#pragma unroll
                for (int j = 0; j < 4; j++) O[i][j] = fmaf(a[i], bb[j], O[i][j]);
        }
        __syncthreads();          // before next chunk's staging overwrites KtP/Vs
    }
    float* __restrict__ attL = ws + O_ATTL;   // [2][2][8192][64]
#pragma unroll
    for (int i = 0; i < 4; i++) {
        const int q = q0 + ty * 4 + i;
        const float inv = 1.f / fmaxf(l_s[ty * 4 + i], 1e-30f);
        *(float4*)&attL[((b * 2 + lh) * 8192 + q) * 64 + tx * 4] =
            make_float4(O[i][0] * inv, O[i][1] * inv, O[i][2] * inv, O[i][3] * inv);
    }
}

// ---------------- output projection + bias ----------------
__launch_bounds__(256)
__global__ void k_out(const float* __restrict__ Wo,
                      const float* __restrict__ bo,
                      const float* __restrict__ ws,
                      float* __restrict__ out) {
    __shared__ float As[16][128];
    __shared__ float Bs[16][128];
    const float* __restrict__ attG = ws + O_K;      // [16384][384]
    const float* __restrict__ attL = ws + O_ATTL;   // [4][8192][64]
    const int r0 = blockIdx.x * 128, c0 = blockIdx.y * 128;
    const int tid = threadIdx.x, tx = tid & 15, ty = tid >> 4;
    const int am = tid >> 1, ako = (tid & 1) * 8;
    const int bk = tid >> 4, bjo = (tid & 15) * 8;
    float acc[8][8];
#pragma unroll
    for (int i = 0; i < 8; i++)
#pragma unroll
        for (int j = 0; j < 8; j++) acc[i][j] = 0.f;

    for (int k0 = 0; k0 < 512; k0 += 16) {
        const int row = r0 + am;
        float4 a0, a1;
        if (k0 < 384) {
            a0 = *(const float4*)(attG + row * 384 + k0 + ako);
            a1 = *(const float4*)(attG + row * 384 + k0 + ako + 4);
        } else {
            const int bb = row >> 13, nn = row & 8191;
            const int kk0 = k0 + ako - 384;
            const int lhh = kk0 >> 6, dd = kk0 & 63;
            const float* src = attL + ((bb * 2 + lhh) * 8192 + nn) * 64 + dd;
            a0 = *(const float4*)(src);
            a1 = *(const float4*)(src + 4);
        }
        float4 b0 = *(const float4*)(Wo + (k0 + bk) * 512 + c0 + bjo);
        float4 b1 = *(const float4*)(Wo + (k0 + bk) * 512 + c0 + bjo + 4);
        As[ako + 0][am] = a0.x; As[ako + 1][am] = a0.y;
        As[ako + 2][am] = a0.z; As[ako + 3][am] = a0.w;
        As[ako + 4][am] = a1.x; As[ako + 5][am] = a1.y;
        As[ako + 6][am] = a1.z; As[ako + 7][am] = a1.w;
        *(float4*)&Bs[bk][bjo]     = b0;
        *(float4*)&Bs[bk][bjo + 4] = b1;
        __syncthreads();
#pragma unroll
        for (int kk = 0; kk < 16; kk++) {
            float4 a04 = *(float4*)&As[kk][ty * 8];
            float4 a14 = *(float4*)&As[kk][ty * 8 + 4];
            float4 b04 = *(float4*)&Bs[kk][tx * 4];
            float4 b14 = *(float4*)&Bs[kk][64 + tx * 4];
            float a[8] = {a04.x, a04.y, a04.z, a04.w, a14.x, a14.y, a14.z, a14.w};
            float b[8] = {b04.x, b04.y, b04.z, b04.w, b14.x, b14.y, b14.z, b14.w};
#pragma unroll
            for (int i = 0; i < 8; i++)
#pragma unroll
                for (int j = 0; j < 8; j++) acc[i][j] = fmaf(a[i], b[j], acc[i][j]);
        }
        __syncthreads();
    }
    const int col0 = c0 + tx * 4, col1 = c0 + 64 + tx * 4;
    float4 bo0 = *(const float4*)(bo + col0);
    float4 bo1 = *(const float4*)(bo + col1);
#pragma unroll
    for (int i = 0; i < 8; i++) {
        int r = r0 + ty * 8 + i;
        *(float4*)&out[r * 512 + col0] =
            make_float4(acc[i][0] + bo0.x, acc[i][1] + bo0.y, acc[i][2] + bo0.z, acc[i][3] + bo0.w);
        *(float4*)&out[r * 512 + col1] =
            make_float4(acc[i][4] + bo1.x, acc[i][5] + bo1.y, acc[i][6] + bo1.z, acc[i][7] + bo1.w);
    }
}

extern "C" void kernel_launch(void* const* d_in, const int* in_sizes, int n_in,
                              void* d_out, int out_size, void* d_ws, size_t ws_size,
                              hipStream_t stream) {
    const float* x    = (const float*)d_in[0];
    const float* Wq   = (const float*)d_in[1];
    const float* Wk   = (const float*)d_in[2];
    const float* Wv   = (const float*)d_in[3];
    const float* Wo   = (const float*)d_in[4];
    const float* bo   = (const float*)d_in[5];
    const float* proj = (const float*)d_in[6];
    float* ws = (float*)d_ws;
    float* out = (float*)d_out;

    hipMemsetAsync(d_ws, 0, (size_t)O_ZEND * 4, stream);                 // kmax/ksum/ctx
    hipLaunchKernelGGL(k_rope,   dim3(1024), dim3(256), 0, stream, ws);
    hipLaunchKernelGGL(k_half_w, dim3(8, 8, 3), dim3(256), 0, stream, Wq, Wk, Wv, ws);
    hipLaunchKernelGGL(k_qkv,    dim3(128, 4, 3), dim3(256), 0, stream, x, ws);
    hipLaunchKernelGGL(k_kmax,   dim3(12, 128), dim3(256), 0, stream, proj, ws);
    hipLaunchKernelGGL(k_kctx,   dim3(12, 32, 2), dim3(256), 0, stream, proj, ws);
    hipLaunchKernelGGL(k_local,  dim3(4, 128), dim3(256), 0, stream, ws);   // before k_qout!
    hipLaunchKernelGGL(k_qout,   dim3(12, 128), dim3(256), 0, stream, proj, ws);
    hipLaunchKernelGGL(k_out,    dim3(128, 4), dim3(256), 0, stream, Wo, bo, ws, out);
}